// Round 2
// baseline (298.982 us; speedup 1.0000x reference)
//
#include <hip/hip_runtime.h>
#include <math.h>

// Problem constants (fixed by setup_inputs): B=2, C=19, H=W=512, fp32 in/out.
constexpr int H = 512, W = 512, B = 2;
constexpr int HW = H * W;

typedef __attribute__((ext_vector_type(8))) short short8;
typedef __attribute__((ext_vector_type(4))) float floatx4;
typedef __attribute__((ext_vector_type(4))) unsigned int uint4v;

__device__ inline unsigned short f2bf(float f) {
  union { float f; unsigned int u; } x{f};
  const unsigned int u = x.u;
  return (unsigned short)((u + 0x7FFFu + ((u >> 16) & 1u)) >> 16);
}
__device__ inline float bf2f(unsigned short s) {
  union { unsigned int u; float f; } x;
  x.u = (unsigned int)s << 16;
  return x.f;
}
// unpack packed bf16 pair (one dword) -> two floats
__device__ inline void unpk2(unsigned int u, float& lo, float& hi) {
  union { unsigned int u; float f; } a, b;
  a.u = u << 16;
  b.u = u & 0xffff0000u;
  lo = a.f;
  hi = b.f;
}

// ---------------------------------------------------------------------------
// fp32 tiled 3x3 conv 3->16, writes bf16 NHWC packed output [B][H][W][16].
// ---------------------------------------------------------------------------
template <int CIN, int COUT, bool RELU>
__global__ __launch_bounds__(256) void conv3x3_fp32_pack(
    const float* __restrict__ in0, const float* __restrict__ wgt,
    const float* __restrict__ bias, unsigned short* __restrict__ outp) {
  constexpr int TS = 16, TH = 18, LDW = 20;
  __shared__ float tile[CIN][TH][LDW];
  const int tx = threadIdx.x, ty = threadIdx.y;
  const int tid = ty * 16 + tx;
  const int w0 = blockIdx.x * TS, h0 = blockIdx.y * TS, b = blockIdx.z;

  for (int idx = tid; idx < CIN * TH * TH; idx += 256) {
    const int cin = idx / (TH * TH);
    const int rem = idx - cin * (TH * TH);
    const int r = rem / TH, c = rem - r * TH;
    const int gh = h0 + r - 1, gw = w0 + c - 1;
    float v = 0.f;
    if ((unsigned)gh < (unsigned)H && (unsigned)gw < (unsigned)W)
      v = in0[(size_t)(b * CIN + cin) * HW + gh * W + gw];
    tile[cin][r][c] = v;
  }
  __syncthreads();

  float acc[COUT];
#pragma unroll
  for (int co = 0; co < COUT; ++co) acc[co] = bias[co];
  for (int cin = 0; cin < CIN; ++cin) {
#pragma unroll
    for (int t = 0; t < 9; ++t) {
      const int ky = t / 3, kx = t - ky * 3;
      const float v = tile[cin][ty + ky][tx + kx];
#pragma unroll
      for (int co = 0; co < COUT; ++co)
        acc[co] = fmaf(v, wgt[(co * CIN + cin) * 9 + t], acc[co]);
    }
  }
  const int oh = h0 + ty, ow = w0 + tx;
  unsigned int pk[COUT / 2];
#pragma unroll
  for (int c2 = 0; c2 < COUT / 2; ++c2) {
    float a0 = acc[2 * c2], a1 = acc[2 * c2 + 1];
    if (RELU) { a0 = fmaxf(a0, 0.f); a1 = fmaxf(a1, 0.f); }
    pk[c2] = (unsigned)f2bf(a0) | ((unsigned)f2bf(a1) << 16);
  }
  unsigned short* dst = outp + ((size_t)(b * H + oh) * W + ow) * COUT;
#pragma unroll
  for (int u = 0; u < COUT / 8; ++u)
    *(uint4v*)(dst + u * 8) = uint4v{pk[u * 4], pk[u * 4 + 1], pk[u * 4 + 2], pk[u * 4 + 3]};
}

// ---------------------------------------------------------------------------
// Weight repack into B-fragment order for mfma_f32_16x16x32_bf16.
// k = tap*CINP + cin (CINP mult of 8 so 8-runs stay within one tap).
// ---------------------------------------------------------------------------
template <int CIN, int CINP, int COUT, int KS>
__global__ __launch_bounds__(256) void repack_w(
    const float* __restrict__ w, unsigned short* __restrict__ bp) {
  constexpr int NT = COUT / 16;
  const int idx = blockIdx.x * 256 + threadIdx.x;
  if (idx >= NT * KS * 512) return;
  const int j = idx & 7;
  const int l = (idx >> 3) & 63;
  const int ks = (idx >> 9) % KS;
  const int nt = idx / (KS * 512);
  const int co = nt * 16 + (l & 15);
  const int kglob = ks * 32 + (l >> 4) * 8 + j;
  const int tap = kglob / CINP;
  const int cin = kglob % CINP;
  float v = 0.f;
  if (tap < 9 && cin < CIN) v = w[((size_t)co * CIN + cin) * 9 + tap];
  bp[idx] = f2bf(v);
}

// ---------------------------------------------------------------------------
// Implicit-GEMM 3x3 conv via bf16 MFMA. Packed bf16 NHWC input [H][W][CINP].
// EPI=0: packed bf16 NHWC output [H][W][NT*16] (bias+relu, direct stores).
// EPI=1: fused 1x1 16->19 (intra head): conv out (bias+relu, bf16) bounced
//        through LDS, then per-pixel 1x1 (no relu) -> packed [H][W][24]
//        (ch19..23 zeroed). Replaces the intra1x1 global round-trip.
// EPI=2: fused 1x1 32->11 + sigmoid + normalize (guide head): conv out
//        bounced through LDS, per-pixel head -> fp32 planes [B][11][HW].
//        Replaces the guide3 global round-trip (saves ~67 MB HBM).
// EDGE19: staging overwrites channel 19 with bf16(edg[pixel]).
// ---------------------------------------------------------------------------
template <int CINP, int KS, int NT, bool EDGE19, int EPI>
__global__ __launch_bounds__(256) void conv3x3_mfma(
    const unsigned short* __restrict__ inp, const float* __restrict__ edg,
    const unsigned short* __restrict__ bpack, const float* __restrict__ bias,
    const float* __restrict__ ew, const float* __restrict__ eb,
    unsigned short* __restrict__ outp, float* __restrict__ outf) {
  constexpr int COUT = NT * 16;
  constexpr int CS = (CINP == 16) ? 24 : 40;  // LDS cin stride (16B mult)
  constexpr int EPS = (EPI == 1) ? 24 : 40;   // epilogue LDS px stride
  __shared__ __align__(16) unsigned short tile[18 * 34 * CS];

  const int tid = threadIdx.x;
  const int w0 = blockIdx.x * 32, h0 = blockIdx.y * 16, b = blockIdx.z;

  // ---- stage halo'd tile: packed pixel copy (dwordx4), zero for OOB ----
  for (int idx = tid; idx < 18 * 34; idx += 256) {
    const int r = idx / 34, c = idx - r * 34;
    const int gh = h0 + r - 1, gw = w0 + c - 1;
    unsigned short* dst = tile + (size_t)(r * 34 + c) * CS;
    if ((unsigned)gh < (unsigned)H && (unsigned)gw < (unsigned)W) {
      const unsigned short* src = inp + ((size_t)(b * H + gh) * W + gw) * CINP;
#pragma unroll
      for (int u = 0; u < CINP / 8; ++u)
        *(uint4v*)(dst + u * 8) = *(const uint4v*)(src + u * 8);
      if (EDGE19) dst[19] = f2bf(edg[(size_t)b * HW + gh * W + gw]);
    } else {
#pragma unroll
      for (int u = 0; u < CINP / 8; ++u)
        *(uint4v*)(dst + u * 8) = uint4v{0, 0, 0, 0};
    }
  }
  __syncthreads();

  // ---- K-loop (fully unrolled) ----
  const int wv = tid >> 6, lane = tid & 63;
  const int q = lane >> 4, l15 = lane & 15;
  const int rb = wv * 4;

  floatx4 acc[8][NT];
#pragma unroll
  for (int mf = 0; mf < 8; ++mf)
#pragma unroll
    for (int nt = 0; nt < NT; ++nt) acc[mf][nt] = floatx4{0.f, 0.f, 0.f, 0.f};

#pragma unroll
  for (int ks = 0; ks < KS; ++ks) {
    short8 bfrag[NT];
#pragma unroll
    for (int nt = 0; nt < NT; ++nt)
      bfrag[nt] = *(const short8*)(bpack + (size_t)(((nt * KS) + ks) * 64 + lane) * 8);

    const int kbase = ks * 32;  // compile-time
    // per-quad k offset: kq = kbase + q*8 -> tap/cin depend on q (runtime but
    // cheap: q in [0,4), only crosses a tap boundary at known points)
    const int kq = kbase + q * 8;
    int tapq = kq / CINP;
    const int cinq = kq % CINP;
    if (tapq > 8) tapq = 8;  // zero-weight pad region
    const int ky = tapq / 3, kx = tapq - ky * 3;
    const unsigned short* aptr =
        tile + (size_t)((rb + ky) * 34 + (l15 + kx)) * CS + cinq;

#pragma unroll
    for (int mf = 0; mf < 8; ++mf) {
      constexpr int mfs[8][2] = {{0,0},{0,16},{1,0},{1,16},{2,0},{2,16},{3,0},{3,16}};
      const int off = (mfs[mf][0] * 34 + mfs[mf][1]) * CS;
      const short8 af = *(const short8*)(aptr + off);
#pragma unroll
      for (int nt = 0; nt < NT; ++nt)
        acc[mf][nt] = __builtin_amdgcn_mfma_f32_16x16x32_bf16(
            af, bfrag[nt], acc[mf][nt], 0, 0, 0);
    }
  }

  if constexpr (EPI == 0) {
    // ---- epilogue: direct bf16 short stores from C-layout registers ----
    // D layout: n (=co within tile) = l15, m (=pixel col) = q*4 + rg.
#pragma unroll
    for (int nt = 0; nt < NT; ++nt) {
      const float bv = bias[nt * 16 + l15];
#pragma unroll
      for (int mf = 0; mf < 8; ++mf) {
        const int row = mf >> 1, colb = (mf & 1) * 16 + q * 4;
        unsigned short* dst =
            outp + ((size_t)(b * H + h0 + rb + row) * W + w0) * COUT + nt * 16 + l15;
#pragma unroll
        for (int rg = 0; rg < 4; ++rg) {
          const float v = fmaxf(acc[mf][nt][rg] + bv, 0.f);
          dst[(size_t)(colb + rg) * COUT] = f2bf(v);
        }
      }
    }
  } else {
    // ---- fused 1x1 epilogue: conv out (bias+relu, bf16) -> LDS ----
    __syncthreads();  // all waves done reading the staging tile
#pragma unroll
    for (int nt = 0; nt < NT; ++nt) {
      const float bv = bias[nt * 16 + l15];
#pragma unroll
      for (int mf = 0; mf < 8; ++mf) {
        const int row = rb + (mf >> 1), colb = (mf & 1) * 16 + q * 4;
#pragma unroll
        for (int rg = 0; rg < 4; ++rg) {
          const int px = row * 32 + colb + rg;
          tile[(size_t)px * EPS + nt * 16 + l15] =
              f2bf(fmaxf(acc[mf][nt][rg] + bv, 0.f));
        }
      }
    }
    __syncthreads();

#pragma unroll
    for (int it = 0; it < 2; ++it) {
      const int p = tid + it * 256;            // 512 px per tile
      const int gh = h0 + (p >> 5), gw = w0 + (p & 31);
      const unsigned short* src = tile + (size_t)p * EPS;

      if constexpr (EPI == 1) {
        // 1x1 conv 16->19 (no relu), pack to [H][W][24] (ch19..23 = 0)
        float xi[16];
        const uint4v r0 = *(const uint4v*)src;
        const uint4v r1 = *(const uint4v*)(src + 8);
        unpk2(r0.x, xi[0], xi[1]);   unpk2(r0.y, xi[2], xi[3]);
        unpk2(r0.z, xi[4], xi[5]);   unpk2(r0.w, xi[6], xi[7]);
        unpk2(r1.x, xi[8], xi[9]);   unpk2(r1.y, xi[10], xi[11]);
        unpk2(r1.z, xi[12], xi[13]); unpk2(r1.w, xi[14], xi[15]);
        float a[19];
#pragma unroll
        for (int co = 0; co < 19; ++co) a[co] = eb[co];
#pragma unroll
        for (int c = 0; c < 16; ++c) {
          const float v = xi[c];
#pragma unroll
          for (int co = 0; co < 19; ++co) a[co] = fmaf(v, ew[co * 16 + c], a[co]);
        }
        unsigned int pk[12];
#pragma unroll
        for (int j = 0; j < 9; ++j)
          pk[j] = (unsigned)f2bf(a[2 * j]) | ((unsigned)f2bf(a[2 * j + 1]) << 16);
        pk[9] = (unsigned)f2bf(a[18]);
        pk[10] = 0; pk[11] = 0;
        unsigned short* dst = outp + ((size_t)(b * H + gh) * W + gw) * 24;
#pragma unroll
        for (int u = 0; u < 3; ++u)
          *(uint4v*)(dst + u * 8) =
              uint4v{pk[u * 4], pk[u * 4 + 1], pk[u * 4 + 2], pk[u * 4 + 3]};
      } else {
        // 1x1 conv 32->11 + sigmoid + normalize -> fp32 planes [B][11][HW]
        float xi[32];
#pragma unroll
        for (int u = 0; u < 4; ++u) {
          const uint4v r = *(const uint4v*)(src + u * 8);
          unpk2(r.x, xi[u * 8 + 0], xi[u * 8 + 1]);
          unpk2(r.y, xi[u * 8 + 2], xi[u * 8 + 3]);
          unpk2(r.z, xi[u * 8 + 4], xi[u * 8 + 5]);
          unpk2(r.w, xi[u * 8 + 6], xi[u * 8 + 7]);
        }
        float g[11], sum = 0.f;
#pragma unroll
        for (int co = 0; co < 11; ++co) {
          float a = eb[co];
#pragma unroll
          for (int c = 0; c < 32; ++c) a = fmaf(xi[c], ew[co * 32 + c], a);
          g[co] = 1.f / (1.f + expf(-a));
          sum += g[co];
        }
        const float inv = 1.f / (sum + 1e-9f);
        const size_t s = (size_t)gh * W + gw;
#pragma unroll
        for (int co = 0; co < 11; ++co)
          outf[(size_t)(b * 11 + co) * HW + s] = g[co] * inv;
      }
    }
  }
}

// ---------------------------------------------------------------------------
// argmax over 19 channels -> float index, 4 pixels/thread
// ---------------------------------------------------------------------------
__global__ __launch_bounds__(256) void argmax_kernel(
    const float* __restrict__ x, float* __restrict__ sx) {
  const int t = blockIdx.x * 256 + threadIdx.x;
  const int b = t / (HW / 4);
  const int s4 = (t - b * (HW / 4)) * 4;
  const float* xp = x + (size_t)b * 19 * HW + s4;
  float4 bv = *(const float4*)xp;
  float ix = 0.f, iy = 0.f, iz = 0.f, iw = 0.f;
#pragma unroll
  for (int c = 1; c < 19; ++c) {
    const float4 v = *(const float4*)(xp + (size_t)c * HW);
    const float fc = (float)c;
    if (v.x > bv.x) { bv.x = v.x; ix = fc; }
    if (v.y > bv.y) { bv.y = v.y; iy = fc; }
    if (v.z > bv.z) { bv.z = v.z; iz = fc; }
    if (v.w > bv.w) { bv.w = v.w; iw = fc; }
  }
  *(float4*)(sx + (size_t)b * HW + s4) = float4{ix, iy, iz, iw};
}

__device__ inline void load_row6(const float* __restrict__ plane, int hh,
                                 int w0, float r[6]) {
#pragma unroll
  for (int i = 0; i < 6; ++i) r[i] = 0.f;
  if ((unsigned)hh < (unsigned)H) {
    const float* rp = plane + (size_t)hh * W + w0;
    const float4 m = *(const float4*)rp;
    r[1] = m.x; r[2] = m.y; r[3] = m.z; r[4] = m.w;
    if (w0 > 0) r[0] = rp[-1];
    if (w0 + 4 < W) r[5] = rp[4];
  }
}

__global__ __launch_bounds__(256) void edge_kernel(
    const float* __restrict__ sx, float* __restrict__ edge) {
  const int t = blockIdx.x * 256 + threadIdx.x;
  const int b = t / (HW / 4);
  const int s4 = (t - b * (HW / 4)) * 4;
  const int h = s4 / W, w0 = s4 - h * W;
  const float* sp = sx + (size_t)b * HW;
  float r0[6], r1[6], r2[6];
  load_row6(sp, h - 1, w0, r0);
  load_row6(sp, h, w0, r1);
  load_row6(sp, h + 1, w0, r2);
  float o[4];
#pragma unroll
  for (int k = 0; k < 4; ++k)
    o[k] = r0[k] + r0[k + 1] + r0[k + 2] + r1[k] + r1[k + 2] + r2[k] +
           r2[k + 1] + r2[k + 2] - 8.f * r1[k + 1];
  *(float4*)(edge + (size_t)b * HW + s4) = float4{o[0], o[1], o[2], o[3]};
}

// ---------------------------------------------------------------------------
// combine, 4 pixels/thread; intra read from packed bf16 [H][W][24].
// Grid = 512 blocks (round-0 form). Round-1 experiment showed this kernel is
// traffic-limited at ~3.5 TB/s regardless of occupancy: the 4-way channel
// split raised occupancy 18->41% but added 40 MB of HBM re-fetch (gf planes
// don't fit per-XCD L2) and regressed 49.6->57.7 us. Keep traffic minimal.
// ---------------------------------------------------------------------------
__global__ __launch_bounds__(256) void combine_kernel(
    const float* __restrict__ x, const unsigned short* __restrict__ intp,
    const float* __restrict__ gf, float* __restrict__ out) {
  const int t = blockIdx.x * 256 + threadIdx.x;
  const int b = t / (HW / 4);
  const int s4 = (t - b * (HW / 4)) * 4;
  const int h = s4 / W, w0 = s4 - h * W;
  const float* gp = gf + (size_t)b * 11 * HW + s4;

  float g[11][4];
#pragma unroll
  for (int m = 0; m < 11; ++m) {
    if (m == 9) continue;  // all-zero shift channel
    const float4 v = *(const float4*)(gp + (size_t)m * HW);
    g[m][0] = v.x; g[m][1] = v.y; g[m][2] = v.z; g[m][3] = v.w;
  }

  const unsigned short* ip = intp + ((size_t)b * HW + s4) * 24;
  for (int c = 0; c < 19; ++c) {
    const float* xc = x + (size_t)(b * 19 + c) * HW;
    float r0[6], r1[6], r2[6];
    load_row6(xc, h - 1, w0, r0);
    load_row6(xc, h, w0, r1);
    load_row6(xc, h + 1, w0, r2);
    float o[4];
#pragma unroll
    for (int k = 0; k < 4; ++k) {
      const float itv = bf2f(ip[(size_t)k * 24 + c]);
      float a = g[0][k] * r1[k + 1];
      a = fmaf(g[1][k], r0[k], a);
      a = fmaf(g[2][k], r0[k + 1], a);
      a = fmaf(g[3][k], r0[k + 2], a);
      a = fmaf(g[4][k], r1[k], a);
      a = fmaf(g[5][k], r1[k + 2], a);
      a = fmaf(g[6][k], r2[k], a);
      a = fmaf(g[7][k], r2[k + 1], a);
      a = fmaf(g[8][k], r2[k + 2], a);
      a = fmaf(g[10][k], itv, a);
      o[k] = a;
    }
    *(float4*)(out + (size_t)(b * 19 + c) * HW + s4) =
        float4{o[0], o[1], o[2], o[3]};
  }
}

// ---------------------------------------------------------------------------
extern "C" void kernel_launch(void* const* d_in, const int* in_sizes, int n_in,
                              void* d_out, int out_size, void* d_ws,
                              size_t ws_size, hipStream_t stream) {
  const float* x     = (const float*)d_in[0];
  const float* image = (const float*)d_in[1];
  const float* iw1 = (const float*)d_in[2];
  const float* ib1 = (const float*)d_in[3];
  const float* iw2 = (const float*)d_in[4];
  const float* ib2 = (const float*)d_in[5];
  const float* iw3 = (const float*)d_in[6];
  const float* ib3 = (const float*)d_in[7];
  const float* gw1 = (const float*)d_in[8];
  const float* gb1 = (const float*)d_in[9];
  const float* gw2 = (const float*)d_in[10];
  const float* gb2 = (const float*)d_in[11];
  const float* gw3 = (const float*)d_in[12];
  const float* gb3 = (const float*)d_in[13];

  // Workspace layout in FLOAT units (1 float = 2 bf16):
  //   sx   [  0,   2)*HW   argmax map
  //   f1p  [  2,  18)*HW   [B][H][W][16] bf16
  //   intp [ 34,  58)*HW   [B][H][W][24] bf16
  //   g1p  [ 58,  90)*HW   [B][H][W][32] bf16
  //   bpacks at 122*HW
  float* ws = (float*)d_ws;
  float* sx = ws;
  unsigned short* f1p  = (unsigned short*)(ws + (size_t)2 * HW);
  unsigned short* intp = (unsigned short*)(ws + (size_t)34 * HW);
  unsigned short* g1p  = (unsigned short*)(ws + (size_t)58 * HW);
  unsigned short* bp_ic2 = (unsigned short*)(ws + (size_t)122 * HW);  // 2560
  unsigned short* bp_gc1 = bp_ic2 + 4096;                             // 7168
  unsigned short* bp_gc2 = bp_gc1 + 12288;                            // 9216

  float* out0 = (float*)d_out;               // (2,19,512,512)
  float* gfo  = out0 + (size_t)2 * 19 * HW;  // (2,11,1,512,512)
  float* edg  = gfo + (size_t)2 * 11 * HW;   // (2,1,512,512)

  const dim3 blk16(16, 16);
  const dim3 grd16(W / 16, H / 16, B);
  const dim3 grdM(W / 32, H / 16, B);
  const int flat4 = (B * HW / 4) / 256;  // 512

  argmax_kernel<<<flat4, 256, 0, stream>>>(x, sx);
  edge_kernel<<<flat4, 256, 0, stream>>>(sx, edg);

  repack_w<16, 16, 16, 5><<<10, 256, 0, stream>>>(iw2, bp_ic2);
  repack_w<20, 24, 32, 7><<<28, 256, 0, stream>>>(gw1, bp_gc1);
  repack_w<32, 32, 32, 9><<<36, 256, 0, stream>>>(gw2, bp_gc2);

  conv3x3_fp32_pack<3, 16, true><<<grd16, blk16, 0, stream>>>(image, iw1, ib1, f1p);
  // intra conv2 (16->16) + fused 1x1 16->19 -> packed intra [H][W][24]
  conv3x3_mfma<16, 5, 1, false, 1><<<grdM, 256, 0, stream>>>(
      f1p, nullptr, bp_ic2, ib2, iw3, ib3, intp, nullptr);
  // guide conv1 (20->32, edge in ch19) -> g1p
  conv3x3_mfma<24, 7, 2, true, 0><<<grdM, 256, 0, stream>>>(
      intp, edg, bp_gc1, gb1, nullptr, nullptr, g1p, nullptr);
  // guide conv2 (32->32) + fused 1x1 32->11 + sigmoid + normalize -> gfo
  conv3x3_mfma<32, 9, 2, false, 2><<<grdM, 256, 0, stream>>>(
      g1p, nullptr, bp_gc2, gb2, gw3, gb3, nullptr, gfo);

  combine_kernel<<<flat4, 256, 0, stream>>>(x, intp, gfo, out0);
}

// Round 3
// 253.133 us; speedup vs baseline: 1.1811x; 1.1811x over previous
//
#include <hip/hip_runtime.h>
#include <math.h>

// Problem constants (fixed by setup_inputs): B=2, C=19, H=W=512, fp32 in/out.
constexpr int H = 512, W = 512, B = 2;
constexpr int HW = H * W;

typedef __attribute__((ext_vector_type(8))) short short8;
typedef __attribute__((ext_vector_type(4))) float floatx4;
typedef __attribute__((ext_vector_type(4))) unsigned int uint4v;

__device__ inline unsigned short f2bf(float f) {
  union { float f; unsigned int u; } x{f};
  const unsigned int u = x.u;
  return (unsigned short)((u + 0x7FFFu + ((u >> 16) & 1u)) >> 16);
}
__device__ inline float bf2f(unsigned short s) {
  union { unsigned int u; float f; } x;
  x.u = (unsigned int)s << 16;
  return x.f;
}
// unpack packed bf16 pair (one dword) -> two floats
__device__ inline void unpk2(unsigned int u, float& lo, float& hi) {
  union { unsigned int u; float f; } a, b;
  a.u = u << 16;
  b.u = u & 0xffff0000u;
  lo = a.f;
  hi = b.f;
}

// ---------------------------------------------------------------------------
// fp32 tiled 3x3 conv 3->16, writes bf16 NHWC packed output [B][H][W][16].
// ---------------------------------------------------------------------------
template <int CIN, int COUT, bool RELU>
__global__ __launch_bounds__(256) void conv3x3_fp32_pack(
    const float* __restrict__ in0, const float* __restrict__ wgt,
    const float* __restrict__ bias, unsigned short* __restrict__ outp) {
  constexpr int TS = 16, TH = 18, LDW = 20;
  __shared__ float tile[CIN][TH][LDW];
  const int tx = threadIdx.x, ty = threadIdx.y;
  const int tid = ty * 16 + tx;
  const int w0 = blockIdx.x * TS, h0 = blockIdx.y * TS, b = blockIdx.z;

  for (int idx = tid; idx < CIN * TH * TH; idx += 256) {
    const int cin = idx / (TH * TH);
    const int rem = idx - cin * (TH * TH);
    const int r = rem / TH, c = rem - r * TH;
    const int gh = h0 + r - 1, gw = w0 + c - 1;
    float v = 0.f;
    if ((unsigned)gh < (unsigned)H && (unsigned)gw < (unsigned)W)
      v = in0[(size_t)(b * CIN + cin) * HW + gh * W + gw];
    tile[cin][r][c] = v;
  }
  __syncthreads();

  float acc[COUT];
#pragma unroll
  for (int co = 0; co < COUT; ++co) acc[co] = bias[co];
  for (int cin = 0; cin < CIN; ++cin) {
#pragma unroll
    for (int t = 0; t < 9; ++t) {
      const int ky = t / 3, kx = t - ky * 3;
      const float v = tile[cin][ty + ky][tx + kx];
#pragma unroll
      for (int co = 0; co < COUT; ++co)
        acc[co] = fmaf(v, wgt[(co * CIN + cin) * 9 + t], acc[co]);
    }
  }
  const int oh = h0 + ty, ow = w0 + tx;
  unsigned int pk[COUT / 2];
#pragma unroll
  for (int c2 = 0; c2 < COUT / 2; ++c2) {
    float a0 = acc[2 * c2], a1 = acc[2 * c2 + 1];
    if (RELU) { a0 = fmaxf(a0, 0.f); a1 = fmaxf(a1, 0.f); }
    pk[c2] = (unsigned)f2bf(a0) | ((unsigned)f2bf(a1) << 16);
  }
  unsigned short* dst = outp + ((size_t)(b * H + oh) * W + ow) * COUT;
#pragma unroll
  for (int u = 0; u < COUT / 8; ++u)
    *(uint4v*)(dst + u * 8) = uint4v{pk[u * 4], pk[u * 4 + 1], pk[u * 4 + 2], pk[u * 4 + 3]};
}

// ---------------------------------------------------------------------------
// Weight repack into B-fragment order for mfma_f32_16x16x32_bf16.
// k = tap*CINP + cin (CINP mult of 8 so 8-runs stay within one tap).
// ---------------------------------------------------------------------------
template <int CIN, int CINP, int COUT, int KS>
__global__ __launch_bounds__(256) void repack_w(
    const float* __restrict__ w, unsigned short* __restrict__ bp) {
  constexpr int NT = COUT / 16;
  const int idx = blockIdx.x * 256 + threadIdx.x;
  if (idx >= NT * KS * 512) return;
  const int j = idx & 7;
  const int l = (idx >> 3) & 63;
  const int ks = (idx >> 9) % KS;
  const int nt = idx / (KS * 512);
  const int co = nt * 16 + (l & 15);
  const int kglob = ks * 32 + (l >> 4) * 8 + j;
  const int tap = kglob / CINP;
  const int cin = kglob % CINP;
  float v = 0.f;
  if (tap < 9 && cin < CIN) v = w[((size_t)co * CIN + cin) * 9 + tap];
  bp[idx] = f2bf(v);
}

// ---------------------------------------------------------------------------
// Implicit-GEMM 3x3 conv via bf16 MFMA. Packed bf16 NHWC input [H][W][CINP].
// Tile = 32x8 px, 4 waves x 2 rows (round-2 post-mortem: the 32x16-tile
// version ran 512 blocks = exactly 2 blocks/CU -> 24% occupancy, everything
// latency-exposed: MfmaUtil 6%, VALU 36%, HBM 9%. 8-row tiles give 2048
// blocks, 27 KB LDS -> 5-6 resident blocks/CU).
// EPI=0: packed bf16 NHWC output [H][W][NT*16] (bias+relu, direct stores).
// EPI=1: fused 1x1 16->19 (intra head) -> packed [H][W][24] (ch19..23=0).
// EPI=2: fused 1x1 32->11 + sigmoid + normalize -> fp32 planes [B][11][HW].
// EDGE19: staging overwrites channel 19 with bf16(edg[pixel]).
// ---------------------------------------------------------------------------
template <int CINP, int KS, int NT, bool EDGE19, int EPI>
__global__ __launch_bounds__(256) void conv3x3_mfma(
    const unsigned short* __restrict__ inp, const float* __restrict__ edg,
    const unsigned short* __restrict__ bpack, const float* __restrict__ bias,
    const float* __restrict__ ew, const float* __restrict__ eb,
    unsigned short* __restrict__ outp, float* __restrict__ outf) {
  constexpr int COUT = NT * 16;
  constexpr int CS = (CINP == 16) ? 24 : 40;  // LDS cin stride (16B mult)
  constexpr int EPS = (EPI == 1) ? 24 : 40;   // epilogue LDS px stride
  constexpr int TR = 10;                      // 8 rows + halo
  __shared__ __align__(16) unsigned short tile[TR * 34 * CS];

  const int tid = threadIdx.x;
  const int w0 = blockIdx.x * 32, h0 = blockIdx.y * 8, b = blockIdx.z;

  // ---- stage halo'd tile: packed pixel copy (dwordx4), zero for OOB ----
  for (int idx = tid; idx < TR * 34; idx += 256) {
    const int r = idx / 34, c = idx - r * 34;
    const int gh = h0 + r - 1, gw = w0 + c - 1;
    unsigned short* dst = tile + (size_t)(r * 34 + c) * CS;
    if ((unsigned)gh < (unsigned)H && (unsigned)gw < (unsigned)W) {
      const unsigned short* src = inp + ((size_t)(b * H + gh) * W + gw) * CINP;
#pragma unroll
      for (int u = 0; u < CINP / 8; ++u)
        *(uint4v*)(dst + u * 8) = *(const uint4v*)(src + u * 8);
      if (EDGE19) dst[19] = f2bf(edg[(size_t)b * HW + gh * W + gw]);
    } else {
#pragma unroll
      for (int u = 0; u < CINP / 8; ++u)
        *(uint4v*)(dst + u * 8) = uint4v{0, 0, 0, 0};
    }
  }
  __syncthreads();

  // ---- K-loop (fully unrolled) ----
  const int wv = tid >> 6, lane = tid & 63;
  const int q = lane >> 4, l15 = lane & 15;
  const int rb = wv * 2;

  floatx4 acc[4][NT];
#pragma unroll
  for (int mf = 0; mf < 4; ++mf)
#pragma unroll
    for (int nt = 0; nt < NT; ++nt) acc[mf][nt] = floatx4{0.f, 0.f, 0.f, 0.f};

#pragma unroll
  for (int ks = 0; ks < KS; ++ks) {
    short8 bfrag[NT];
#pragma unroll
    for (int nt = 0; nt < NT; ++nt)
      bfrag[nt] = *(const short8*)(bpack + (size_t)(((nt * KS) + ks) * 64 + lane) * 8);

    const int kbase = ks * 32;  // compile-time
    // per-quad k offset: kq = kbase + q*8 -> tap/cin depend on q (runtime but
    // cheap: q in [0,4), only crosses a tap boundary at known points)
    const int kq = kbase + q * 8;
    int tapq = kq / CINP;
    const int cinq = kq % CINP;
    if (tapq > 8) tapq = 8;  // zero-weight pad region
    const int ky = tapq / 3, kx = tapq - ky * 3;
    const unsigned short* aptr =
        tile + (size_t)((rb + ky) * 34 + (l15 + kx)) * CS + cinq;

#pragma unroll
    for (int mf = 0; mf < 4; ++mf) {
      constexpr int mfs[4][2] = {{0, 0}, {0, 16}, {1, 0}, {1, 16}};
      const int off = (mfs[mf][0] * 34 + mfs[mf][1]) * CS;
      const short8 af = *(const short8*)(aptr + off);
#pragma unroll
      for (int nt = 0; nt < NT; ++nt)
        acc[mf][nt] = __builtin_amdgcn_mfma_f32_16x16x32_bf16(
            af, bfrag[nt], acc[mf][nt], 0, 0, 0);
    }
  }

  if constexpr (EPI == 0) {
    // ---- epilogue: direct bf16 short stores from C-layout registers ----
    // D layout: n (=co within tile) = l15, m (=pixel col) = q*4 + rg.
#pragma unroll
    for (int nt = 0; nt < NT; ++nt) {
      const float bv = bias[nt * 16 + l15];
#pragma unroll
      for (int mf = 0; mf < 4; ++mf) {
        const int row = mf >> 1, colb = (mf & 1) * 16 + q * 4;
        unsigned short* dst =
            outp + ((size_t)(b * H + h0 + rb + row) * W + w0) * COUT + nt * 16 + l15;
#pragma unroll
        for (int rg = 0; rg < 4; ++rg) {
          const float v = fmaxf(acc[mf][nt][rg] + bv, 0.f);
          dst[(size_t)(colb + rg) * COUT] = f2bf(v);
        }
      }
    }
  } else {
    // ---- fused 1x1 epilogue: conv out (bias+relu, bf16) -> LDS ----
    __syncthreads();  // all waves done reading the staging tile
#pragma unroll
    for (int nt = 0; nt < NT; ++nt) {
      const float bv = bias[nt * 16 + l15];
#pragma unroll
      for (int mf = 0; mf < 4; ++mf) {
        const int row = rb + (mf >> 1), colb = (mf & 1) * 16 + q * 4;
#pragma unroll
        for (int rg = 0; rg < 4; ++rg) {
          const int px = row * 32 + colb + rg;
          tile[(size_t)px * EPS + nt * 16 + l15] =
              f2bf(fmaxf(acc[mf][nt][rg] + bv, 0.f));
        }
      }
    }
    __syncthreads();

    {
      const int p = tid;                       // 256 px per tile, 1/thread
      const int gh = h0 + (p >> 5), gw = w0 + (p & 31);
      const unsigned short* src = tile + (size_t)p * EPS;

      if constexpr (EPI == 1) {
        // 1x1 conv 16->19 (no relu), pack to [H][W][24] (ch19..23 = 0)
        float xi[16];
        const uint4v r0 = *(const uint4v*)src;
        const uint4v r1 = *(const uint4v*)(src + 8);
        unpk2(r0.x, xi[0], xi[1]);   unpk2(r0.y, xi[2], xi[3]);
        unpk2(r0.z, xi[4], xi[5]);   unpk2(r0.w, xi[6], xi[7]);
        unpk2(r1.x, xi[8], xi[9]);   unpk2(r1.y, xi[10], xi[11]);
        unpk2(r1.z, xi[12], xi[13]); unpk2(r1.w, xi[14], xi[15]);
        float a[19];
#pragma unroll
        for (int co = 0; co < 19; ++co) a[co] = eb[co];
#pragma unroll
        for (int c = 0; c < 16; ++c) {
          const float v = xi[c];
#pragma unroll
          for (int co = 0; co < 19; ++co) a[co] = fmaf(v, ew[co * 16 + c], a[co]);
        }
        unsigned int pk[12];
#pragma unroll
        for (int j = 0; j < 9; ++j)
          pk[j] = (unsigned)f2bf(a[2 * j]) | ((unsigned)f2bf(a[2 * j + 1]) << 16);
        pk[9] = (unsigned)f2bf(a[18]);
        pk[10] = 0; pk[11] = 0;
        unsigned short* dst = outp + ((size_t)(b * H + gh) * W + gw) * 24;
#pragma unroll
        for (int u = 0; u < 3; ++u)
          *(uint4v*)(dst + u * 8) =
              uint4v{pk[u * 4], pk[u * 4 + 1], pk[u * 4 + 2], pk[u * 4 + 3]};
      } else {
        // 1x1 conv 32->11 + sigmoid + normalize -> fp32 planes [B][11][HW]
        float xi[32];
#pragma unroll
        for (int u = 0; u < 4; ++u) {
          const uint4v r = *(const uint4v*)(src + u * 8);
          unpk2(r.x, xi[u * 8 + 0], xi[u * 8 + 1]);
          unpk2(r.y, xi[u * 8 + 2], xi[u * 8 + 3]);
          unpk2(r.z, xi[u * 8 + 4], xi[u * 8 + 5]);
          unpk2(r.w, xi[u * 8 + 6], xi[u * 8 + 7]);
        }
        float g[11], sum = 0.f;
#pragma unroll
        for (int co = 0; co < 11; ++co) {
          float a = eb[co];
#pragma unroll
          for (int c = 0; c < 32; ++c) a = fmaf(xi[c], ew[co * 32 + c], a);
          g[co] = 1.f / (1.f + expf(-a));
          sum += g[co];
        }
        const float inv = 1.f / (sum + 1e-9f);
        const size_t s = (size_t)gh * W + gw;
#pragma unroll
        for (int co = 0; co < 11; ++co)
          outf[(size_t)(b * 11 + co) * HW + s] = g[co] * inv;
      }
    }
  }
}

// ---------------------------------------------------------------------------
// argmax over 19 channels -> float index, 4 pixels/thread
// ---------------------------------------------------------------------------
__global__ __launch_bounds__(256) void argmax_kernel(
    const float* __restrict__ x, float* __restrict__ sx) {
  const int t = blockIdx.x * 256 + threadIdx.x;
  const int b = t / (HW / 4);
  const int s4 = (t - b * (HW / 4)) * 4;
  const float* xp = x + (size_t)b * 19 * HW + s4;
  float4 bv = *(const float4*)xp;
  float ix = 0.f, iy = 0.f, iz = 0.f, iw = 0.f;
#pragma unroll
  for (int c = 1; c < 19; ++c) {
    const float4 v = *(const float4*)(xp + (size_t)c * HW);
    const float fc = (float)c;
    if (v.x > bv.x) { bv.x = v.x; ix = fc; }
    if (v.y > bv.y) { bv.y = v.y; iy = fc; }
    if (v.z > bv.z) { bv.z = v.z; iz = fc; }
    if (v.w > bv.w) { bv.w = v.w; iw = fc; }
  }
  *(float4*)(sx + (size_t)b * HW + s4) = float4{ix, iy, iz, iw};
}

__device__ inline void load_row6(const float* __restrict__ plane, int hh,
                                 int w0, float r[6]) {
#pragma unroll
  for (int i = 0; i < 6; ++i) r[i] = 0.f;
  if ((unsigned)hh < (unsigned)H) {
    const float* rp = plane + (size_t)hh * W + w0;
    const float4 m = *(const float4*)rp;
    r[1] = m.x; r[2] = m.y; r[3] = m.z; r[4] = m.w;
    if (w0 > 0) r[0] = rp[-1];
    if (w0 + 4 < W) r[5] = rp[4];
  }
}

__global__ __launch_bounds__(256) void edge_kernel(
    const float* __restrict__ sx, float* __restrict__ edge) {
  const int t = blockIdx.x * 256 + threadIdx.x;
  const int b = t / (HW / 4);
  const int s4 = (t - b * (HW / 4)) * 4;
  const int h = s4 / W, w0 = s4 - h * W;
  const float* sp = sx + (size_t)b * HW;
  float r0[6], r1[6], r2[6];
  load_row6(sp, h - 1, w0, r0);
  load_row6(sp, h, w0, r1);
  load_row6(sp, h + 1, w0, r2);
  float o[4];
#pragma unroll
  for (int k = 0; k < 4; ++k)
    o[k] = r0[k] + r0[k + 1] + r0[k + 2] + r1[k] + r1[k + 2] + r2[k] +
           r2[k + 1] + r2[k + 2] - 8.f * r1[k + 1];
  *(float4*)(edge + (size_t)b * HW + s4) = float4{o[0], o[1], o[2], o[3]};
}

// ---------------------------------------------------------------------------
// combine, 4 pixels/thread; intra read from packed bf16 [H][W][24].
// Grid = 512 blocks (round-0 form). Round-1 experiment showed this kernel is
// traffic-limited at ~3.5 TB/s regardless of occupancy: the 4-way channel
// split raised occupancy 18->41% but added 40 MB of HBM re-fetch (gf planes
// don't fit per-XCD L2) and regressed 49.6->57.7 us. Keep traffic minimal.
// ---------------------------------------------------------------------------
__global__ __launch_bounds__(256) void combine_kernel(
    const float* __restrict__ x, const unsigned short* __restrict__ intp,
    const float* __restrict__ gf, float* __restrict__ out) {
  const int t = blockIdx.x * 256 + threadIdx.x;
  const int b = t / (HW / 4);
  const int s4 = (t - b * (HW / 4)) * 4;
  const int h = s4 / W, w0 = s4 - h * W;
  const float* gp = gf + (size_t)b * 11 * HW + s4;

  float g[11][4];
#pragma unroll
  for (int m = 0; m < 11; ++m) {
    if (m == 9) continue;  // all-zero shift channel
    const float4 v = *(const float4*)(gp + (size_t)m * HW);
    g[m][0] = v.x; g[m][1] = v.y; g[m][2] = v.z; g[m][3] = v.w;
  }

  const unsigned short* ip = intp + ((size_t)b * HW + s4) * 24;
  for (int c = 0; c < 19; ++c) {
    const float* xc = x + (size_t)(b * 19 + c) * HW;
    float r0[6], r1[6], r2[6];
    load_row6(xc, h - 1, w0, r0);
    load_row6(xc, h, w0, r1);
    load_row6(xc, h + 1, w0, r2);
    float o[4];
#pragma unroll
    for (int k = 0; k < 4; ++k) {
      const float itv = bf2f(ip[(size_t)k * 24 + c]);
      float a = g[0][k] * r1[k + 1];
      a = fmaf(g[1][k], r0[k], a);
      a = fmaf(g[2][k], r0[k + 1], a);
      a = fmaf(g[3][k], r0[k + 2], a);
      a = fmaf(g[4][k], r1[k], a);
      a = fmaf(g[5][k], r1[k + 2], a);
      a = fmaf(g[6][k], r2[k], a);
      a = fmaf(g[7][k], r2[k + 1], a);
      a = fmaf(g[8][k], r2[k + 2], a);
      a = fmaf(g[10][k], itv, a);
      o[k] = a;
    }
    *(float4*)(out + (size_t)(b * 19 + c) * HW + s4) =
        float4{o[0], o[1], o[2], o[3]};
  }
}

// ---------------------------------------------------------------------------
extern "C" void kernel_launch(void* const* d_in, const int* in_sizes, int n_in,
                              void* d_out, int out_size, void* d_ws,
                              size_t ws_size, hipStream_t stream) {
  const float* x     = (const float*)d_in[0];
  const float* image = (const float*)d_in[1];
  const float* iw1 = (const float*)d_in[2];
  const float* ib1 = (const float*)d_in[3];
  const float* iw2 = (const float*)d_in[4];
  const float* ib2 = (const float*)d_in[5];
  const float* iw3 = (const float*)d_in[6];
  const float* ib3 = (const float*)d_in[7];
  const float* gw1 = (const float*)d_in[8];
  const float* gb1 = (const float*)d_in[9];
  const float* gw2 = (const float*)d_in[10];
  const float* gb2 = (const float*)d_in[11];
  const float* gw3 = (const float*)d_in[12];
  const float* gb3 = (const float*)d_in[13];

  // Workspace layout in FLOAT units (1 float = 2 bf16):
  //   sx   [  0,   2)*HW   argmax map
  //   f1p  [  2,  18)*HW   [B][H][W][16] bf16
  //   intp [ 34,  58)*HW   [B][H][W][24] bf16
  //   g1p  [ 58,  90)*HW   [B][H][W][32] bf16
  //   bpacks at 122*HW
  float* ws = (float*)d_ws;
  float* sx = ws;
  unsigned short* f1p  = (unsigned short*)(ws + (size_t)2 * HW);
  unsigned short* intp = (unsigned short*)(ws + (size_t)34 * HW);
  unsigned short* g1p  = (unsigned short*)(ws + (size_t)58 * HW);
  unsigned short* bp_ic2 = (unsigned short*)(ws + (size_t)122 * HW);  // 2560
  unsigned short* bp_gc1 = bp_ic2 + 4096;                             // 7168
  unsigned short* bp_gc2 = bp_gc1 + 12288;                            // 9216

  float* out0 = (float*)d_out;               // (2,19,512,512)
  float* gfo  = out0 + (size_t)2 * 19 * HW;  // (2,11,1,512,512)
  float* edg  = gfo + (size_t)2 * 11 * HW;   // (2,1,512,512)

  const dim3 blk16(16, 16);
  const dim3 grd16(W / 16, H / 16, B);
  const dim3 grdM(W / 32, H / 8, B);  // 32x8 tiles -> 2048 blocks
  const int flat4 = (B * HW / 4) / 256;  // 512

  argmax_kernel<<<flat4, 256, 0, stream>>>(x, sx);
  edge_kernel<<<flat4, 256, 0, stream>>>(sx, edg);

  repack_w<16, 16, 16, 5><<<10, 256, 0, stream>>>(iw2, bp_ic2);
  repack_w<20, 24, 32, 7><<<28, 256, 0, stream>>>(gw1, bp_gc1);
  repack_w<32, 32, 32, 9><<<36, 256, 0, stream>>>(gw2, bp_gc2);

  conv3x3_fp32_pack<3, 16, true><<<grd16, blk16, 0, stream>>>(image, iw1, ib1, f1p);
  // intra conv2 (16->16) + fused 1x1 16->19 -> packed intra [H][W][24]
  conv3x3_mfma<16, 5, 1, false, 1><<<grdM, 256, 0, stream>>>(
      f1p, nullptr, bp_ic2, ib2, iw3, ib3, intp, nullptr);
  // guide conv1 (20->32, edge in ch19) -> g1p
  conv3x3_mfma<24, 7, 2, true, 0><<<grdM, 256, 0, stream>>>(
      intp, edg, bp_gc1, gb1, nullptr, nullptr, g1p, nullptr);
  // guide conv2 (32->32) + fused 1x1 32->11 + sigmoid + normalize -> gfo
  conv3x3_mfma<32, 9, 2, false, 2><<<grdM, 256, 0, stream>>>(
      g1p, nullptr, bp_gc2, gb2, gw3, gb3, nullptr, gfo);

  combine_kernel<<<flat4, 256, 0, stream>>>(x, intp, gfo, out0);
}

// Round 4
// 251.803 us; speedup vs baseline: 1.1874x; 1.0053x over previous
//
#include <hip/hip_runtime.h>
#include <math.h>

// Problem constants (fixed by setup_inputs): B=2, C=19, H=W=512, fp32 in/out.
constexpr int H = 512, W = 512, B = 2;
constexpr int HW = H * W;

typedef __attribute__((ext_vector_type(8))) short short8;
typedef __attribute__((ext_vector_type(4))) float floatx4;
typedef __attribute__((ext_vector_type(4))) unsigned int uint4v;

__device__ inline unsigned short f2bf(float f) {
  union { float f; unsigned int u; } x{f};
  const unsigned int u = x.u;
  return (unsigned short)((u + 0x7FFFu + ((u >> 16) & 1u)) >> 16);
}
__device__ inline float bf2f(unsigned short s) {
  union { unsigned int u; float f; } x;
  x.u = (unsigned int)s << 16;
  return x.f;
}
// unpack packed bf16 pair (one dword) -> two floats
__device__ inline void unpk2(unsigned int u, float& lo, float& hi) {
  union { unsigned int u; float f; } a, b;
  a.u = u << 16;
  b.u = u & 0xffff0000u;
  lo = a.f;
  hi = b.f;
}

// ---------------------------------------------------------------------------
// fp32 tiled 3x3 conv 3->16, writes bf16 NHWC packed output [B][H][W][16].
// ---------------------------------------------------------------------------
template <int CIN, int COUT, bool RELU>
__global__ __launch_bounds__(256) void conv3x3_fp32_pack(
    const float* __restrict__ in0, const float* __restrict__ wgt,
    const float* __restrict__ bias, unsigned short* __restrict__ outp) {
  constexpr int TS = 16, TH = 18, LDW = 20;
  __shared__ float tile[CIN][TH][LDW];
  const int tx = threadIdx.x, ty = threadIdx.y;
  const int tid = ty * 16 + tx;
  const int w0 = blockIdx.x * TS, h0 = blockIdx.y * TS, b = blockIdx.z;

  for (int idx = tid; idx < CIN * TH * TH; idx += 256) {
    const int cin = idx / (TH * TH);
    const int rem = idx - cin * (TH * TH);
    const int r = rem / TH, c = rem - r * TH;
    const int gh = h0 + r - 1, gw = w0 + c - 1;
    float v = 0.f;
    if ((unsigned)gh < (unsigned)H && (unsigned)gw < (unsigned)W)
      v = in0[(size_t)(b * CIN + cin) * HW + gh * W + gw];
    tile[cin][r][c] = v;
  }
  __syncthreads();

  float acc[COUT];
#pragma unroll
  for (int co = 0; co < COUT; ++co) acc[co] = bias[co];
  for (int cin = 0; cin < CIN; ++cin) {
#pragma unroll
    for (int t = 0; t < 9; ++t) {
      const int ky = t / 3, kx = t - ky * 3;
      const float v = tile[cin][ty + ky][tx + kx];
#pragma unroll
      for (int co = 0; co < COUT; ++co)
        acc[co] = fmaf(v, wgt[(co * CIN + cin) * 9 + t], acc[co]);
    }
  }
  const int oh = h0 + ty, ow = w0 + tx;
  unsigned int pk[COUT / 2];
#pragma unroll
  for (int c2 = 0; c2 < COUT / 2; ++c2) {
    float a0 = acc[2 * c2], a1 = acc[2 * c2 + 1];
    if (RELU) { a0 = fmaxf(a0, 0.f); a1 = fmaxf(a1, 0.f); }
    pk[c2] = (unsigned)f2bf(a0) | ((unsigned)f2bf(a1) << 16);
  }
  unsigned short* dst = outp + ((size_t)(b * H + oh) * W + ow) * COUT;
#pragma unroll
  for (int u = 0; u < COUT / 8; ++u)
    *(uint4v*)(dst + u * 8) = uint4v{pk[u * 4], pk[u * 4 + 1], pk[u * 4 + 2], pk[u * 4 + 3]};
}

// ---------------------------------------------------------------------------
// Weight repack into B-fragment order for mfma_f32_16x16x32_bf16.
// k = tap*CINP + cin (CINP mult of 8 so 8-runs stay within one tap).
// ---------------------------------------------------------------------------
template <int CIN, int CINP, int COUT, int KS>
__global__ __launch_bounds__(256) void repack_w(
    const float* __restrict__ w, unsigned short* __restrict__ bp) {
  constexpr int NT = COUT / 16;
  const int idx = blockIdx.x * 256 + threadIdx.x;
  if (idx >= NT * KS * 512) return;
  const int j = idx & 7;
  const int l = (idx >> 3) & 63;
  const int ks = (idx >> 9) % KS;
  const int nt = idx / (KS * 512);
  const int co = nt * 16 + (l & 15);
  const int kglob = ks * 32 + (l >> 4) * 8 + j;
  const int tap = kglob / CINP;
  const int cin = kglob % CINP;
  float v = 0.f;
  if (tap < 9 && cin < CIN) v = w[((size_t)co * CIN + cin) * 9 + tap];
  bp[idx] = f2bf(v);
}

// ---------------------------------------------------------------------------
// Implicit-GEMM 3x3 conv via bf16 MFMA. Packed bf16 NHWC input [H][W][CINP].
// Tile = 32x8 px, 4 waves x 2 rows (round-2 post-mortem: the 32x16-tile
// version ran 512 blocks = exactly 2 blocks/CU -> 24% occupancy, everything
// latency-exposed. 8-row tiles give 2048 blocks, 27 KB LDS -> 5-6 resident
// blocks/CU; round-3 confirmed conv dispatches fell out of the top-5).
// EPI=0: packed bf16 NHWC output [H][W][NT*16] (bias+relu, direct stores).
// EPI=1: fused 1x1 16->19 (intra head) -> packed [H][W][24] (ch19..23=0).
// EPI=2: fused 1x1 32->11 + sigmoid + normalize -> fp32 planes [B][11][HW].
// EDGE19: staging overwrites channel 19 with bf16(edg[pixel]).
// ---------------------------------------------------------------------------
template <int CINP, int KS, int NT, bool EDGE19, int EPI>
__global__ __launch_bounds__(256) void conv3x3_mfma(
    const unsigned short* __restrict__ inp, const float* __restrict__ edg,
    const unsigned short* __restrict__ bpack, const float* __restrict__ bias,
    const float* __restrict__ ew, const float* __restrict__ eb,
    unsigned short* __restrict__ outp, float* __restrict__ outf) {
  constexpr int COUT = NT * 16;
  constexpr int CS = (CINP == 16) ? 24 : 40;  // LDS cin stride (16B mult)
  constexpr int EPS = (EPI == 1) ? 24 : 40;   // epilogue LDS px stride
  constexpr int TR = 10;                      // 8 rows + halo
  __shared__ __align__(16) unsigned short tile[TR * 34 * CS];

  const int tid = threadIdx.x;
  const int w0 = blockIdx.x * 32, h0 = blockIdx.y * 8, b = blockIdx.z;

  // ---- stage halo'd tile: packed pixel copy (dwordx4), zero for OOB ----
  for (int idx = tid; idx < TR * 34; idx += 256) {
    const int r = idx / 34, c = idx - r * 34;
    const int gh = h0 + r - 1, gw = w0 + c - 1;
    unsigned short* dst = tile + (size_t)(r * 34 + c) * CS;
    if ((unsigned)gh < (unsigned)H && (unsigned)gw < (unsigned)W) {
      const unsigned short* src = inp + ((size_t)(b * H + gh) * W + gw) * CINP;
#pragma unroll
      for (int u = 0; u < CINP / 8; ++u)
        *(uint4v*)(dst + u * 8) = *(const uint4v*)(src + u * 8);
      if (EDGE19) dst[19] = f2bf(edg[(size_t)b * HW + gh * W + gw]);
    } else {
#pragma unroll
      for (int u = 0; u < CINP / 8; ++u)
        *(uint4v*)(dst + u * 8) = uint4v{0, 0, 0, 0};
    }
  }
  __syncthreads();

  // ---- K-loop (fully unrolled) ----
  const int wv = tid >> 6, lane = tid & 63;
  const int q = lane >> 4, l15 = lane & 15;
  const int rb = wv * 2;

  floatx4 acc[4][NT];
#pragma unroll
  for (int mf = 0; mf < 4; ++mf)
#pragma unroll
    for (int nt = 0; nt < NT; ++nt) acc[mf][nt] = floatx4{0.f, 0.f, 0.f, 0.f};

#pragma unroll
  for (int ks = 0; ks < KS; ++ks) {
    short8 bfrag[NT];
#pragma unroll
    for (int nt = 0; nt < NT; ++nt)
      bfrag[nt] = *(const short8*)(bpack + (size_t)(((nt * KS) + ks) * 64 + lane) * 8);

    const int kbase = ks * 32;  // compile-time
    // per-quad k offset: kq = kbase + q*8 -> tap/cin depend on q (runtime but
    // cheap: q in [0,4), only crosses a tap boundary at known points)
    const int kq = kbase + q * 8;
    int tapq = kq / CINP;
    const int cinq = kq % CINP;
    if (tapq > 8) tapq = 8;  // zero-weight pad region
    const int ky = tapq / 3, kx = tapq - ky * 3;
    const unsigned short* aptr =
        tile + (size_t)((rb + ky) * 34 + (l15 + kx)) * CS + cinq;

#pragma unroll
    for (int mf = 0; mf < 4; ++mf) {
      constexpr int mfs[4][2] = {{0, 0}, {0, 16}, {1, 0}, {1, 16}};
      const int off = (mfs[mf][0] * 34 + mfs[mf][1]) * CS;
      const short8 af = *(const short8*)(aptr + off);
#pragma unroll
      for (int nt = 0; nt < NT; ++nt)
        acc[mf][nt] = __builtin_amdgcn_mfma_f32_16x16x32_bf16(
            af, bfrag[nt], acc[mf][nt], 0, 0, 0);
    }
  }

  if constexpr (EPI == 0) {
    // ---- epilogue: direct bf16 short stores from C-layout registers ----
    // D layout: n (=co within tile) = l15, m (=pixel col) = q*4 + rg.
#pragma unroll
    for (int nt = 0; nt < NT; ++nt) {
      const float bv = bias[nt * 16 + l15];
#pragma unroll
      for (int mf = 0; mf < 4; ++mf) {
        const int row = mf >> 1, colb = (mf & 1) * 16 + q * 4;
        unsigned short* dst =
            outp + ((size_t)(b * H + h0 + rb + row) * W + w0) * COUT + nt * 16 + l15;
#pragma unroll
        for (int rg = 0; rg < 4; ++rg) {
          const float v = fmaxf(acc[mf][nt][rg] + bv, 0.f);
          dst[(size_t)(colb + rg) * COUT] = f2bf(v);
        }
      }
    }
  } else {
    // ---- fused 1x1 epilogue: conv out (bias+relu, bf16) -> LDS ----
    __syncthreads();  // all waves done reading the staging tile
#pragma unroll
    for (int nt = 0; nt < NT; ++nt) {
      const float bv = bias[nt * 16 + l15];
#pragma unroll
      for (int mf = 0; mf < 4; ++mf) {
        const int row = rb + (mf >> 1), colb = (mf & 1) * 16 + q * 4;
#pragma unroll
        for (int rg = 0; rg < 4; ++rg) {
          const int px = row * 32 + colb + rg;
          tile[(size_t)px * EPS + nt * 16 + l15] =
              f2bf(fmaxf(acc[mf][nt][rg] + bv, 0.f));
        }
      }
    }
    __syncthreads();

    {
      const int p = tid;                       // 256 px per tile, 1/thread
      const int gh = h0 + (p >> 5), gw = w0 + (p & 31);
      const unsigned short* src = tile + (size_t)p * EPS;

      if constexpr (EPI == 1) {
        // 1x1 conv 16->19 (no relu), pack to [H][W][24] (ch19..23 = 0)
        float xi[16];
        const uint4v r0 = *(const uint4v*)src;
        const uint4v r1 = *(const uint4v*)(src + 8);
        unpk2(r0.x, xi[0], xi[1]);   unpk2(r0.y, xi[2], xi[3]);
        unpk2(r0.z, xi[4], xi[5]);   unpk2(r0.w, xi[6], xi[7]);
        unpk2(r1.x, xi[8], xi[9]);   unpk2(r1.y, xi[10], xi[11]);
        unpk2(r1.z, xi[12], xi[13]); unpk2(r1.w, xi[14], xi[15]);
        float a[19];
#pragma unroll
        for (int co = 0; co < 19; ++co) a[co] = eb[co];
#pragma unroll
        for (int c = 0; c < 16; ++c) {
          const float v = xi[c];
#pragma unroll
          for (int co = 0; co < 19; ++co) a[co] = fmaf(v, ew[co * 16 + c], a[co]);
        }
        unsigned int pk[12];
#pragma unroll
        for (int j = 0; j < 9; ++j)
          pk[j] = (unsigned)f2bf(a[2 * j]) | ((unsigned)f2bf(a[2 * j + 1]) << 16);
        pk[9] = (unsigned)f2bf(a[18]);
        pk[10] = 0; pk[11] = 0;
        unsigned short* dst = outp + ((size_t)(b * H + gh) * W + gw) * 24;
#pragma unroll
        for (int u = 0; u < 3; ++u)
          *(uint4v*)(dst + u * 8) =
              uint4v{pk[u * 4], pk[u * 4 + 1], pk[u * 4 + 2], pk[u * 4 + 3]};
      } else {
        // 1x1 conv 32->11 + sigmoid + normalize -> fp32 planes [B][11][HW]
        float xi[32];
#pragma unroll
        for (int u = 0; u < 4; ++u) {
          const uint4v r = *(const uint4v*)(src + u * 8);
          unpk2(r.x, xi[u * 8 + 0], xi[u * 8 + 1]);
          unpk2(r.y, xi[u * 8 + 2], xi[u * 8 + 3]);
          unpk2(r.z, xi[u * 8 + 4], xi[u * 8 + 5]);
          unpk2(r.w, xi[u * 8 + 6], xi[u * 8 + 7]);
        }
        float g[11], sum = 0.f;
#pragma unroll
        for (int co = 0; co < 11; ++co) {
          float a = eb[co];
#pragma unroll
          for (int c = 0; c < 32; ++c) a = fmaf(xi[c], ew[co * 32 + c], a);
          g[co] = 1.f / (1.f + expf(-a));
          sum += g[co];
        }
        const float inv = 1.f / (sum + 1e-9f);
        const size_t s = (size_t)gh * W + gw;
#pragma unroll
        for (int co = 0; co < 11; ++co)
          outf[(size_t)(b * 11 + co) * HW + s] = g[co] * inv;
      }
    }
  }
}

// ---------------------------------------------------------------------------
// argmax over 19 channels -> float index, 2 pixels/thread (round-4: grid-size
// was the occupancy cap at 4 px/thread; 2 px doubles waves, traffic equal).
// ---------------------------------------------------------------------------
__global__ __launch_bounds__(256) void argmax_kernel(
    const float* __restrict__ x, float* __restrict__ sx) {
  const int t = blockIdx.x * 256 + threadIdx.x;  // [0, B*HW/2)
  const int b = t / (HW / 2);
  const int s2 = (t - b * (HW / 2)) * 2;
  const float* xp = x + (size_t)b * 19 * HW + s2;
  float2 bv = *(const float2*)xp;
  float ix = 0.f, iy = 0.f;
#pragma unroll
  for (int c = 1; c < 19; ++c) {
    const float2 v = *(const float2*)(xp + (size_t)c * HW);
    const float fc = (float)c;
    if (v.x > bv.x) { bv.x = v.x; ix = fc; }
    if (v.y > bv.y) { bv.y = v.y; iy = fc; }
  }
  *(float2*)(sx + (size_t)b * HW + s2) = float2{ix, iy};
}

// 4-wide row load for 2-px-per-thread stencils: r[1] = col w0 (w0 even).
__device__ inline void load_row4(const float* __restrict__ plane, int hh,
                                 int w0, float r[4]) {
#pragma unroll
  for (int i = 0; i < 4; ++i) r[i] = 0.f;
  if ((unsigned)hh < (unsigned)H) {
    const float* rp = plane + (size_t)hh * W + w0;
    const float2 m = *(const float2*)rp;
    r[1] = m.x; r[2] = m.y;
    if (w0 > 0) r[0] = rp[-1];
    if (w0 + 2 < W) r[3] = rp[2];
  }
}

__global__ __launch_bounds__(256) void edge_kernel(
    const float* __restrict__ sx, float* __restrict__ edge) {
  const int t = blockIdx.x * 256 + threadIdx.x;  // [0, B*HW/2)
  const int b = t / (HW / 2);
  const int s2 = (t - b * (HW / 2)) * 2;
  const int h = s2 / W, w0 = s2 - h * W;
  const float* sp = sx + (size_t)b * HW;
  float r0[4], r1[4], r2[4];
  load_row4(sp, h - 1, w0, r0);
  load_row4(sp, h, w0, r1);
  load_row4(sp, h + 1, w0, r2);
  float o[2];
#pragma unroll
  for (int k = 0; k < 2; ++k)
    o[k] = r0[k] + r0[k + 1] + r0[k + 2] + r1[k] + r1[k + 2] + r2[k] +
           r2[k + 1] + r2[k + 2] - 8.f * r1[k + 1];
  *(float2*)(edge + (size_t)b * HW + s2) = float2{o[0], o[1]};
}

// ---------------------------------------------------------------------------
// combine, 2 pixels/thread; intra read from packed bf16 [H][W][24].
// Traffic is already at the floor (round-3: FETCH 126 MB = x 80 + intp 25 +
// gf 23). Round-1 showed channel-splitting ADDS traffic (gf re-fetch) and
// loses. This version keeps traffic identical and doubles wave count
// (4 px -> 2 px per thread: 512 -> 1024 blocks, 2 -> 4 waves/SIMD) to hide
// latency; round-3 counters: occ 19%, VALU 8%, HBM 41% = latency-bound.
// ---------------------------------------------------------------------------
__global__ __launch_bounds__(256) void combine_kernel(
    const float* __restrict__ x, const unsigned short* __restrict__ intp,
    const float* __restrict__ gf, float* __restrict__ out) {
  const int t = blockIdx.x * 256 + threadIdx.x;  // [0, B*HW/2)
  const int b = t / (HW / 2);
  const int s2 = (t - b * (HW / 2)) * 2;
  const int h = s2 / W, w0 = s2 - h * W;
  const float* gp = gf + (size_t)b * 11 * HW + s2;

  float g[11][2];
#pragma unroll
  for (int m = 0; m < 11; ++m) {
    if (m == 9) continue;  // all-zero shift channel
    const float2 v = *(const float2*)(gp + (size_t)m * HW);
    g[m][0] = v.x; g[m][1] = v.y;
  }

  const unsigned short* ip = intp + ((size_t)b * HW + s2) * 24;
  for (int c = 0; c < 19; ++c) {
    const float* xc = x + (size_t)(b * 19 + c) * HW;
    float r0[4], r1[4], r2[4];
    load_row4(xc, h - 1, w0, r0);
    load_row4(xc, h, w0, r1);
    load_row4(xc, h + 1, w0, r2);
    float o[2];
#pragma unroll
    for (int k = 0; k < 2; ++k) {
      const float itv = bf2f(ip[(size_t)k * 24 + c]);
      float a = g[0][k] * r1[k + 1];
      a = fmaf(g[1][k], r0[k], a);
      a = fmaf(g[2][k], r0[k + 1], a);
      a = fmaf(g[3][k], r0[k + 2], a);
      a = fmaf(g[4][k], r1[k], a);
      a = fmaf(g[5][k], r1[k + 2], a);
      a = fmaf(g[6][k], r2[k], a);
      a = fmaf(g[7][k], r2[k + 1], a);
      a = fmaf(g[8][k], r2[k + 2], a);
      a = fmaf(g[10][k], itv, a);
      o[k] = a;
    }
    *(float2*)(out + (size_t)(b * 19 + c) * HW + s2) = float2{o[0], o[1]};
  }
}

// ---------------------------------------------------------------------------
extern "C" void kernel_launch(void* const* d_in, const int* in_sizes, int n_in,
                              void* d_out, int out_size, void* d_ws,
                              size_t ws_size, hipStream_t stream) {
  const float* x     = (const float*)d_in[0];
  const float* image = (const float*)d_in[1];
  const float* iw1 = (const float*)d_in[2];
  const float* ib1 = (const float*)d_in[3];
  const float* iw2 = (const float*)d_in[4];
  const float* ib2 = (const float*)d_in[5];
  const float* iw3 = (const float*)d_in[6];
  const float* ib3 = (const float*)d_in[7];
  const float* gw1 = (const float*)d_in[8];
  const float* gb1 = (const float*)d_in[9];
  const float* gw2 = (const float*)d_in[10];
  const float* gb2 = (const float*)d_in[11];
  const float* gw3 = (const float*)d_in[12];
  const float* gb3 = (const float*)d_in[13];

  // Workspace layout in FLOAT units (1 float = 2 bf16):
  //   sx   [  0,   2)*HW   argmax map
  //   f1p  [  2,  18)*HW   [B][H][W][16] bf16
  //   intp [ 34,  58)*HW   [B][H][W][24] bf16
  //   g1p  [ 58,  90)*HW   [B][H][W][32] bf16
  //   bpacks at 122*HW
  float* ws = (float*)d_ws;
  float* sx = ws;
  unsigned short* f1p  = (unsigned short*)(ws + (size_t)2 * HW);
  unsigned short* intp = (unsigned short*)(ws + (size_t)34 * HW);
  unsigned short* g1p  = (unsigned short*)(ws + (size_t)58 * HW);
  unsigned short* bp_ic2 = (unsigned short*)(ws + (size_t)122 * HW);  // 2560
  unsigned short* bp_gc1 = bp_ic2 + 4096;                             // 7168
  unsigned short* bp_gc2 = bp_gc1 + 12288;                            // 9216

  float* out0 = (float*)d_out;               // (2,19,512,512)
  float* gfo  = out0 + (size_t)2 * 19 * HW;  // (2,11,1,512,512)
  float* edg  = gfo + (size_t)2 * 11 * HW;   // (2,1,512,512)

  const dim3 blk16(16, 16);
  const dim3 grd16(W / 16, H / 16, B);
  const dim3 grdM(W / 32, H / 8, B);     // 32x8 tiles -> 2048 blocks
  const int flat2 = (B * HW / 2) / 256;  // 1024 blocks, 2 px/thread

  argmax_kernel<<<flat2, 256, 0, stream>>>(x, sx);
  edge_kernel<<<flat2, 256, 0, stream>>>(sx, edg);

  repack_w<16, 16, 16, 5><<<10, 256, 0, stream>>>(iw2, bp_ic2);
  repack_w<20, 24, 32, 7><<<28, 256, 0, stream>>>(gw1, bp_gc1);
  repack_w<32, 32, 32, 9><<<36, 256, 0, stream>>>(gw2, bp_gc2);

  conv3x3_fp32_pack<3, 16, true><<<grd16, blk16, 0, stream>>>(image, iw1, ib1, f1p);
  // intra conv2 (16->16) + fused 1x1 16->19 -> packed intra [H][W][24]
  conv3x3_mfma<16, 5, 1, false, 1><<<grdM, 256, 0, stream>>>(
      f1p, nullptr, bp_ic2, ib2, iw3, ib3, intp, nullptr);
  // guide conv1 (20->32, edge in ch19) -> g1p
  conv3x3_mfma<24, 7, 2, true, 0><<<grdM, 256, 0, stream>>>(
      intp, edg, bp_gc1, gb1, nullptr, nullptr, g1p, nullptr);
  // guide conv2 (32->32) + fused 1x1 32->11 + sigmoid + normalize -> gfo
  conv3x3_mfma<32, 9, 2, false, 2><<<grdM, 256, 0, stream>>>(
      g1p, nullptr, bp_gc2, gb2, gw3, gb3, nullptr, gfo);

  combine_kernel<<<flat2, 256, 0, stream>>>(x, intp, gfo, out0);
}

// Round 5
// 242.736 us; speedup vs baseline: 1.2317x; 1.0374x over previous
//
#include <hip/hip_runtime.h>
#include <math.h>

// Problem constants (fixed by setup_inputs): B=2, C=19, H=W=512, fp32 in/out.
constexpr int H = 512, W = 512, B = 2;
constexpr int HW = H * W;

typedef __attribute__((ext_vector_type(8))) short short8;
typedef __attribute__((ext_vector_type(4))) float floatx4;
typedef __attribute__((ext_vector_type(4))) unsigned int uint4v;

__device__ inline unsigned short f2bf(float f) {
  union { float f; unsigned int u; } x{f};
  const unsigned int u = x.u;
  return (unsigned short)((u + 0x7FFFu + ((u >> 16) & 1u)) >> 16);
}
__device__ inline float bf2f(unsigned short s) {
  union { unsigned int u; float f; } x;
  x.u = (unsigned int)s << 16;
  return x.f;
}
// unpack packed bf16 pair (one dword) -> two floats
__device__ inline void unpk2(unsigned int u, float& lo, float& hi) {
  union { unsigned int u; float f; } a, b;
  a.u = u << 16;
  b.u = u & 0xffff0000u;
  lo = a.f;
  hi = b.f;
}

// ---------------------------------------------------------------------------
// fp32 tiled 3x3 conv 3->16, writes bf16 NHWC packed output [B][H][W][16].
// ---------------------------------------------------------------------------
template <int CIN, int COUT, bool RELU>
__global__ __launch_bounds__(256) void conv3x3_fp32_pack(
    const float* __restrict__ in0, const float* __restrict__ wgt,
    const float* __restrict__ bias, unsigned short* __restrict__ outp) {
  constexpr int TS = 16, TH = 18, LDW = 20;
  __shared__ float tile[CIN][TH][LDW];
  const int tx = threadIdx.x, ty = threadIdx.y;
  const int tid = ty * 16 + tx;
  const int w0 = blockIdx.x * TS, h0 = blockIdx.y * TS, b = blockIdx.z;

  for (int idx = tid; idx < CIN * TH * TH; idx += 256) {
    const int cin = idx / (TH * TH);
    const int rem = idx - cin * (TH * TH);
    const int r = rem / TH, c = rem - r * TH;
    const int gh = h0 + r - 1, gw = w0 + c - 1;
    float v = 0.f;
    if ((unsigned)gh < (unsigned)H && (unsigned)gw < (unsigned)W)
      v = in0[(size_t)(b * CIN + cin) * HW + gh * W + gw];
    tile[cin][r][c] = v;
  }
  __syncthreads();

  float acc[COUT];
#pragma unroll
  for (int co = 0; co < COUT; ++co) acc[co] = bias[co];
  for (int cin = 0; cin < CIN; ++cin) {
#pragma unroll
    for (int t = 0; t < 9; ++t) {
      const int ky = t / 3, kx = t - ky * 3;
      const float v = tile[cin][ty + ky][tx + kx];
#pragma unroll
      for (int co = 0; co < COUT; ++co)
        acc[co] = fmaf(v, wgt[(co * CIN + cin) * 9 + t], acc[co]);
    }
  }
  const int oh = h0 + ty, ow = w0 + tx;
  unsigned int pk[COUT / 2];
#pragma unroll
  for (int c2 = 0; c2 < COUT / 2; ++c2) {
    float a0 = acc[2 * c2], a1 = acc[2 * c2 + 1];
    if (RELU) { a0 = fmaxf(a0, 0.f); a1 = fmaxf(a1, 0.f); }
    pk[c2] = (unsigned)f2bf(a0) | ((unsigned)f2bf(a1) << 16);
  }
  unsigned short* dst = outp + ((size_t)(b * H + oh) * W + ow) * COUT;
#pragma unroll
  for (int u = 0; u < COUT / 8; ++u)
    *(uint4v*)(dst + u * 8) = uint4v{pk[u * 4], pk[u * 4 + 1], pk[u * 4 + 2], pk[u * 4 + 3]};
}

// ---------------------------------------------------------------------------
// Weight repack into B-fragment order for mfma_f32_16x16x32_bf16.
// k = tap*CINP + cin (CINP mult of 8 so 8-runs stay within one tap).
// ---------------------------------------------------------------------------
template <int CIN, int CINP, int COUT, int KS>
__global__ __launch_bounds__(256) void repack_w(
    const float* __restrict__ w, unsigned short* __restrict__ bp) {
  constexpr int NT = COUT / 16;
  const int idx = blockIdx.x * 256 + threadIdx.x;
  if (idx >= NT * KS * 512) return;
  const int j = idx & 7;
  const int l = (idx >> 3) & 63;
  const int ks = (idx >> 9) % KS;
  const int nt = idx / (KS * 512);
  const int co = nt * 16 + (l & 15);
  const int kglob = ks * 32 + (l >> 4) * 8 + j;
  const int tap = kglob / CINP;
  const int cin = kglob % CINP;
  float v = 0.f;
  if (tap < 9 && cin < CIN) v = w[((size_t)co * CIN + cin) * 9 + tap];
  bp[idx] = f2bf(v);
}

// ---------------------------------------------------------------------------
// Implicit-GEMM 3x3 conv via bf16 MFMA. Packed bf16 NHWC input [H][W][CINP].
// Tile = 32x8 px, 4 waves x 2 rows (round-2 post-mortem: the 32x16-tile
// version ran 512 blocks = exactly 2 blocks/CU -> 24% occupancy, everything
// latency-exposed. 8-row tiles give 2048 blocks, 27 KB LDS -> 5-6 resident
// blocks/CU; round-3 confirmed conv dispatches fell out of the top-5).
// EPI=0: packed bf16 NHWC output [H][W][NT*16] (bias+relu, direct stores).
// EPI=1: fused 1x1 16->19 (intra head) -> packed [H][W][24] (ch19..23=0).
// EPI=2: fused 1x1 32->11 + sigmoid + normalize -> fp32 planes [B][11][HW].
// EDGE19: staging overwrites channel 19 with bf16(edg[pixel]).
// ---------------------------------------------------------------------------
template <int CINP, int KS, int NT, bool EDGE19, int EPI>
__global__ __launch_bounds__(256) void conv3x3_mfma(
    const unsigned short* __restrict__ inp, const float* __restrict__ edg,
    const unsigned short* __restrict__ bpack, const float* __restrict__ bias,
    const float* __restrict__ ew, const float* __restrict__ eb,
    unsigned short* __restrict__ outp, float* __restrict__ outf) {
  constexpr int COUT = NT * 16;
  constexpr int CS = (CINP == 16) ? 24 : 40;  // LDS cin stride (16B mult)
  constexpr int EPS = (EPI == 1) ? 24 : 40;   // epilogue LDS px stride
  constexpr int TR = 10;                      // 8 rows + halo
  __shared__ __align__(16) unsigned short tile[TR * 34 * CS];

  const int tid = threadIdx.x;
  const int w0 = blockIdx.x * 32, h0 = blockIdx.y * 8, b = blockIdx.z;

  // ---- stage halo'd tile: packed pixel copy (dwordx4), zero for OOB ----
  for (int idx = tid; idx < TR * 34; idx += 256) {
    const int r = idx / 34, c = idx - r * 34;
    const int gh = h0 + r - 1, gw = w0 + c - 1;
    unsigned short* dst = tile + (size_t)(r * 34 + c) * CS;
    if ((unsigned)gh < (unsigned)H && (unsigned)gw < (unsigned)W) {
      const unsigned short* src = inp + ((size_t)(b * H + gh) * W + gw) * CINP;
#pragma unroll
      for (int u = 0; u < CINP / 8; ++u)
        *(uint4v*)(dst + u * 8) = *(const uint4v*)(src + u * 8);
      if (EDGE19) dst[19] = f2bf(edg[(size_t)b * HW + gh * W + gw]);
    } else {
#pragma unroll
      for (int u = 0; u < CINP / 8; ++u)
        *(uint4v*)(dst + u * 8) = uint4v{0, 0, 0, 0};
    }
  }
  __syncthreads();

  // ---- K-loop (fully unrolled) ----
  const int wv = tid >> 6, lane = tid & 63;
  const int q = lane >> 4, l15 = lane & 15;
  const int rb = wv * 2;

  floatx4 acc[4][NT];
#pragma unroll
  for (int mf = 0; mf < 4; ++mf)
#pragma unroll
    for (int nt = 0; nt < NT; ++nt) acc[mf][nt] = floatx4{0.f, 0.f, 0.f, 0.f};

#pragma unroll
  for (int ks = 0; ks < KS; ++ks) {
    short8 bfrag[NT];
#pragma unroll
    for (int nt = 0; nt < NT; ++nt)
      bfrag[nt] = *(const short8*)(bpack + (size_t)(((nt * KS) + ks) * 64 + lane) * 8);

    const int kbase = ks * 32;  // compile-time
    // per-quad k offset: kq = kbase + q*8 -> tap/cin depend on q (runtime but
    // cheap: q in [0,4), only crosses a tap boundary at known points)
    const int kq = kbase + q * 8;
    int tapq = kq / CINP;
    const int cinq = kq % CINP;
    if (tapq > 8) tapq = 8;  // zero-weight pad region
    const int ky = tapq / 3, kx = tapq - ky * 3;
    const unsigned short* aptr =
        tile + (size_t)((rb + ky) * 34 + (l15 + kx)) * CS + cinq;

#pragma unroll
    for (int mf = 0; mf < 4; ++mf) {
      constexpr int mfs[4][2] = {{0, 0}, {0, 16}, {1, 0}, {1, 16}};
      const int off = (mfs[mf][0] * 34 + mfs[mf][1]) * CS;
      const short8 af = *(const short8*)(aptr + off);
#pragma unroll
      for (int nt = 0; nt < NT; ++nt)
        acc[mf][nt] = __builtin_amdgcn_mfma_f32_16x16x32_bf16(
            af, bfrag[nt], acc[mf][nt], 0, 0, 0);
    }
  }

  if constexpr (EPI == 0) {
    // ---- epilogue: direct bf16 short stores from C-layout registers ----
    // D layout: n (=co within tile) = l15, m (=pixel col) = q*4 + rg.
#pragma unroll
    for (int nt = 0; nt < NT; ++nt) {
      const float bv = bias[nt * 16 + l15];
#pragma unroll
      for (int mf = 0; mf < 4; ++mf) {
        const int row = mf >> 1, colb = (mf & 1) * 16 + q * 4;
        unsigned short* dst =
            outp + ((size_t)(b * H + h0 + rb + row) * W + w0) * COUT + nt * 16 + l15;
#pragma unroll
        for (int rg = 0; rg < 4; ++rg) {
          const float v = fmaxf(acc[mf][nt][rg] + bv, 0.f);
          dst[(size_t)(colb + rg) * COUT] = f2bf(v);
        }
      }
    }
  } else {
    // ---- fused 1x1 epilogue: conv out (bias+relu, bf16) -> LDS ----
    __syncthreads();  // all waves done reading the staging tile
#pragma unroll
    for (int nt = 0; nt < NT; ++nt) {
      const float bv = bias[nt * 16 + l15];
#pragma unroll
      for (int mf = 0; mf < 4; ++mf) {
        const int row = rb + (mf >> 1), colb = (mf & 1) * 16 + q * 4;
#pragma unroll
        for (int rg = 0; rg < 4; ++rg) {
          const int px = row * 32 + colb + rg;
          tile[(size_t)px * EPS + nt * 16 + l15] =
              f2bf(fmaxf(acc[mf][nt][rg] + bv, 0.f));
        }
      }
    }
    __syncthreads();

    {
      const int p = tid;                       // 256 px per tile, 1/thread
      const int gh = h0 + (p >> 5), gw = w0 + (p & 31);
      const unsigned short* src = tile + (size_t)p * EPS;

      if constexpr (EPI == 1) {
        // 1x1 conv 16->19 (no relu), pack to [H][W][24] (ch19..23 = 0)
        float xi[16];
        const uint4v r0 = *(const uint4v*)src;
        const uint4v r1 = *(const uint4v*)(src + 8);
        unpk2(r0.x, xi[0], xi[1]);   unpk2(r0.y, xi[2], xi[3]);
        unpk2(r0.z, xi[4], xi[5]);   unpk2(r0.w, xi[6], xi[7]);
        unpk2(r1.x, xi[8], xi[9]);   unpk2(r1.y, xi[10], xi[11]);
        unpk2(r1.z, xi[12], xi[13]); unpk2(r1.w, xi[14], xi[15]);
        float a[19];
#pragma unroll
        for (int co = 0; co < 19; ++co) a[co] = eb[co];
#pragma unroll
        for (int c = 0; c < 16; ++c) {
          const float v = xi[c];
#pragma unroll
          for (int co = 0; co < 19; ++co) a[co] = fmaf(v, ew[co * 16 + c], a[co]);
        }
        unsigned int pk[12];
#pragma unroll
        for (int j = 0; j < 9; ++j)
          pk[j] = (unsigned)f2bf(a[2 * j]) | ((unsigned)f2bf(a[2 * j + 1]) << 16);
        pk[9] = (unsigned)f2bf(a[18]);
        pk[10] = 0; pk[11] = 0;
        unsigned short* dst = outp + ((size_t)(b * H + gh) * W + gw) * 24;
#pragma unroll
        for (int u = 0; u < 3; ++u)
          *(uint4v*)(dst + u * 8) =
              uint4v{pk[u * 4], pk[u * 4 + 1], pk[u * 4 + 2], pk[u * 4 + 3]};
      } else {
        // 1x1 conv 32->11 + sigmoid + normalize -> fp32 planes [B][11][HW]
        float xi[32];
#pragma unroll
        for (int u = 0; u < 4; ++u) {
          const uint4v r = *(const uint4v*)(src + u * 8);
          unpk2(r.x, xi[u * 8 + 0], xi[u * 8 + 1]);
          unpk2(r.y, xi[u * 8 + 2], xi[u * 8 + 3]);
          unpk2(r.z, xi[u * 8 + 4], xi[u * 8 + 5]);
          unpk2(r.w, xi[u * 8 + 6], xi[u * 8 + 7]);
        }
        float g[11], sum = 0.f;
#pragma unroll
        for (int co = 0; co < 11; ++co) {
          float a = eb[co];
#pragma unroll
          for (int c = 0; c < 32; ++c) a = fmaf(xi[c], ew[co * 32 + c], a);
          g[co] = 1.f / (1.f + expf(-a));
          sum += g[co];
        }
        const float inv = 1.f / (sum + 1e-9f);
        const size_t s = (size_t)gh * W + gw;
#pragma unroll
        for (int co = 0; co < 11; ++co)
          outf[(size_t)(b * 11 + co) * HW + s] = g[co] * inv;
      }
    }
  }
}

// ---------------------------------------------------------------------------
// argmax over 19 channels -> float index, 1 pixel/thread (round-5: grid-size
// is the occupancy cap; 1 px = 2048 blocks = 8 waves/SIMD. Scalar loads are
// still 256 B/wave coalesced).
// ---------------------------------------------------------------------------
__global__ __launch_bounds__(256) void argmax_kernel(
    const float* __restrict__ x, float* __restrict__ sx) {
  const int t = blockIdx.x * 256 + threadIdx.x;  // [0, B*HW)
  const int b = t >> 18;
  const int s = t & (HW - 1);
  const float* xp = x + (size_t)b * 19 * HW + s;
  float bv = *xp;
  float ix = 0.f;
#pragma unroll
  for (int c = 1; c < 19; ++c) {
    const float v = xp[(size_t)c * HW];
    if (v > bv) { bv = v; ix = (float)c; }
  }
  sx[(size_t)b * HW + s] = ix;
}

// 4-wide row load for 2-px-per-thread stencils: r[1] = col w0 (w0 even).
__device__ inline void load_row4(const float* __restrict__ plane, int hh,
                                 int w0, float r[4]) {
#pragma unroll
  for (int i = 0; i < 4; ++i) r[i] = 0.f;
  if ((unsigned)hh < (unsigned)H) {
    const float* rp = plane + (size_t)hh * W + w0;
    const float2 m = *(const float2*)rp;
    r[1] = m.x; r[2] = m.y;
    if (w0 > 0) r[0] = rp[-1];
    if (w0 + 2 < W) r[3] = rp[2];
  }
}

__global__ __launch_bounds__(256) void edge_kernel(
    const float* __restrict__ sx, float* __restrict__ edge) {
  const int t = blockIdx.x * 256 + threadIdx.x;  // [0, B*HW/2)
  const int b = t / (HW / 2);
  const int s2 = (t - b * (HW / 2)) * 2;
  const int h = s2 / W, w0 = s2 - h * W;
  const float* sp = sx + (size_t)b * HW;
  float r0[4], r1[4], r2[4];
  load_row4(sp, h - 1, w0, r0);
  load_row4(sp, h, w0, r1);
  load_row4(sp, h + 1, w0, r2);
  float o[2];
#pragma unroll
  for (int k = 0; k < 2; ++k)
    o[k] = r0[k] + r0[k + 1] + r0[k + 2] + r1[k] + r1[k + 2] + r2[k] +
           r2[k + 1] + r2[k + 2] - 8.f * r1[k + 1];
  *(float2*)(edge + (size_t)b * HW + s2) = float2{o[0], o[1]};
}

// 3-wide row load for 1-px-per-thread stencils: r[1] = col w.
__device__ inline void load_row3(const float* __restrict__ plane, int hh,
                                 int w, float r[3]) {
  r[0] = 0.f; r[1] = 0.f; r[2] = 0.f;
  if ((unsigned)hh < (unsigned)H) {
    const float* rp = plane + (size_t)hh * W + w;
    r[1] = rp[0];
    if (w > 0) r[0] = rp[-1];
    if (w + 1 < W) r[2] = rp[1];
  }
}

// ---------------------------------------------------------------------------
// combine, 1 pixel/thread; intra read from packed bf16 [H][W][24].
// Traffic floor reached in round 4 (FETCH 92 MB ~= read-once 88 MB; the
// half-row-per-block layout gets x row h+-1 reuse from L2). Round-4 counters
// (occ 31%, VALU 12%, HBM 35%) say latency-bound with the grid capped at
// 4 waves/SIMD (1024 blocks). 1 px/thread -> 2048 blocks -> 8 waves/SIMD;
// scalar loads remain 256 B/wave coalesced; same row-adjacency so traffic
// should stay ~92 MB (round-1 lesson: never pay traffic for occupancy).
// ---------------------------------------------------------------------------
__global__ __launch_bounds__(256) void combine_kernel(
    const float* __restrict__ x, const unsigned short* __restrict__ intp,
    const float* __restrict__ gf, float* __restrict__ out) {
  const int t = blockIdx.x * 256 + threadIdx.x;  // [0, B*HW)
  const int b = t >> 18;
  const int s = t & (HW - 1);
  const int h = s >> 9, w = s & (W - 1);
  const float* gp = gf + (size_t)b * 11 * HW + s;

  float g[11];
#pragma unroll
  for (int m = 0; m < 11; ++m) {
    if (m == 9) continue;  // all-zero shift channel
    g[m] = gp[(size_t)m * HW];
  }

  const unsigned short* ip = intp + ((size_t)b * HW + s) * 24;
  for (int c = 0; c < 19; ++c) {
    const float* xc = x + (size_t)(b * 19 + c) * HW;
    float r0[3], r1[3], r2[3];
    load_row3(xc, h - 1, w, r0);
    load_row3(xc, h, w, r1);
    load_row3(xc, h + 1, w, r2);
    const float itv = bf2f(ip[c]);
    float a = g[0] * r1[1];
    a = fmaf(g[1], r0[0], a);
    a = fmaf(g[2], r0[1], a);
    a = fmaf(g[3], r0[2], a);
    a = fmaf(g[4], r1[0], a);
    a = fmaf(g[5], r1[2], a);
    a = fmaf(g[6], r2[0], a);
    a = fmaf(g[7], r2[1], a);
    a = fmaf(g[8], r2[2], a);
    a = fmaf(g[10], itv, a);
    out[(size_t)(b * 19 + c) * HW + s] = a;
  }
}

// ---------------------------------------------------------------------------
extern "C" void kernel_launch(void* const* d_in, const int* in_sizes, int n_in,
                              void* d_out, int out_size, void* d_ws,
                              size_t ws_size, hipStream_t stream) {
  const float* x     = (const float*)d_in[0];
  const float* image = (const float*)d_in[1];
  const float* iw1 = (const float*)d_in[2];
  const float* ib1 = (const float*)d_in[3];
  const float* iw2 = (const float*)d_in[4];
  const float* ib2 = (const float*)d_in[5];
  const float* iw3 = (const float*)d_in[6];
  const float* ib3 = (const float*)d_in[7];
  const float* gw1 = (const float*)d_in[8];
  const float* gb1 = (const float*)d_in[9];
  const float* gw2 = (const float*)d_in[10];
  const float* gb2 = (const float*)d_in[11];
  const float* gw3 = (const float*)d_in[12];
  const float* gb3 = (const float*)d_in[13];

  // Workspace layout in FLOAT units (1 float = 2 bf16):
  //   sx   [  0,   2)*HW   argmax map
  //   f1p  [  2,  18)*HW   [B][H][W][16] bf16
  //   intp [ 34,  58)*HW   [B][H][W][24] bf16
  //   g1p  [ 58,  90)*HW   [B][H][W][32] bf16
  //   bpacks at 122*HW
  float* ws = (float*)d_ws;
  float* sx = ws;
  unsigned short* f1p  = (unsigned short*)(ws + (size_t)2 * HW);
  unsigned short* intp = (unsigned short*)(ws + (size_t)34 * HW);
  unsigned short* g1p  = (unsigned short*)(ws + (size_t)58 * HW);
  unsigned short* bp_ic2 = (unsigned short*)(ws + (size_t)122 * HW);  // 2560
  unsigned short* bp_gc1 = bp_ic2 + 4096;                             // 7168
  unsigned short* bp_gc2 = bp_gc1 + 12288;                            // 9216

  float* out0 = (float*)d_out;               // (2,19,512,512)
  float* gfo  = out0 + (size_t)2 * 19 * HW;  // (2,11,1,512,512)
  float* edg  = gfo + (size_t)2 * 11 * HW;   // (2,1,512,512)

  const dim3 blk16(16, 16);
  const dim3 grd16(W / 16, H / 16, B);
  const dim3 grdM(W / 32, H / 8, B);     // 32x8 tiles -> 2048 blocks
  const int flat1 = (B * HW) / 256;      // 2048 blocks, 1 px/thread
  const int flat2 = (B * HW / 2) / 256;  // 1024 blocks, 2 px/thread

  argmax_kernel<<<flat1, 256, 0, stream>>>(x, sx);
  edge_kernel<<<flat2, 256, 0, stream>>>(sx, edg);

  repack_w<16, 16, 16, 5><<<10, 256, 0, stream>>>(iw2, bp_ic2);
  repack_w<20, 24, 32, 7><<<28, 256, 0, stream>>>(gw1, bp_gc1);
  repack_w<32, 32, 32, 9><<<36, 256, 0, stream>>>(gw2, bp_gc2);

  conv3x3_fp32_pack<3, 16, true><<<grd16, blk16, 0, stream>>>(image, iw1, ib1, f1p);
  // intra conv2 (16->16) + fused 1x1 16->19 -> packed intra [H][W][24]
  conv3x3_mfma<16, 5, 1, false, 1><<<grdM, 256, 0, stream>>>(
      f1p, nullptr, bp_ic2, ib2, iw3, ib3, intp, nullptr);
  // guide conv1 (20->32, edge in ch19) -> g1p
  conv3x3_mfma<24, 7, 2, true, 0><<<grdM, 256, 0, stream>>>(
      intp, edg, bp_gc1, gb1, nullptr, nullptr, g1p, nullptr);
  // guide conv2 (32->32) + fused 1x1 32->11 + sigmoid + normalize -> gfo
  conv3x3_mfma<32, 9, 2, false, 2><<<grdM, 256, 0, stream>>>(
      g1p, nullptr, bp_gc2, gb2, gw3, gb3, nullptr, gfo);

  combine_kernel<<<flat1, 256, 0, stream>>>(x, intp, gfo, out0);
}

// Round 6
// 237.783 us; speedup vs baseline: 1.2574x; 1.0208x over previous
//
#include <hip/hip_runtime.h>
#include <math.h>

// Problem constants (fixed by setup_inputs): B=2, C=19, H=W=512, fp32 in/out.
constexpr int H = 512, W = 512, B = 2;
constexpr int HW = H * W;

typedef __attribute__((ext_vector_type(8))) short short8;
typedef __attribute__((ext_vector_type(4))) float floatx4;
typedef __attribute__((ext_vector_type(4))) unsigned int uint4v;

__device__ inline unsigned short f2bf(float f) {
  union { float f; unsigned int u; } x{f};
  const unsigned int u = x.u;
  return (unsigned short)((u + 0x7FFFu + ((u >> 16) & 1u)) >> 16);
}
__device__ inline float bf2f(unsigned short s) {
  union { unsigned int u; float f; } x;
  x.u = (unsigned int)s << 16;
  return x.f;
}
// unpack packed bf16 pair (one dword) -> two floats
__device__ inline void unpk2(unsigned int u, float& lo, float& hi) {
  union { unsigned int u; float f; } a, b;
  a.u = u << 16;
  b.u = u & 0xffff0000u;
  lo = a.f;
  hi = b.f;
}

// 3-wide row load for 1-px-per-thread stencils: r[1] = col w.
__device__ inline void load_row3(const float* __restrict__ plane, int hh,
                                 int w, float r[3]) {
  r[0] = 0.f; r[1] = 0.f; r[2] = 0.f;
  if ((unsigned)hh < (unsigned)H) {
    const float* rp = plane + (size_t)hh * W + w;
    r[1] = rp[0];
    if (w > 0) r[0] = rp[-1];
    if (w + 1 < W) r[2] = rp[1];
  }
}

// ---------------------------------------------------------------------------
// fp32 tiled 3x3 conv 3->16, writes bf16 NHWC packed output [B][H][W][16].
// ---------------------------------------------------------------------------
template <int CIN, int COUT, bool RELU>
__global__ __launch_bounds__(256) void conv3x3_fp32_pack(
    const float* __restrict__ in0, const float* __restrict__ wgt,
    const float* __restrict__ bias, unsigned short* __restrict__ outp) {
  constexpr int TS = 16, TH = 18, LDW = 20;
  __shared__ float tile[CIN][TH][LDW];
  const int tx = threadIdx.x, ty = threadIdx.y;
  const int tid = ty * 16 + tx;
  const int w0 = blockIdx.x * TS, h0 = blockIdx.y * TS, b = blockIdx.z;

  for (int idx = tid; idx < CIN * TH * TH; idx += 256) {
    const int cin = idx / (TH * TH);
    const int rem = idx - cin * (TH * TH);
    const int r = rem / TH, c = rem - r * TH;
    const int gh = h0 + r - 1, gw = w0 + c - 1;
    float v = 0.f;
    if ((unsigned)gh < (unsigned)H && (unsigned)gw < (unsigned)W)
      v = in0[(size_t)(b * CIN + cin) * HW + gh * W + gw];
    tile[cin][r][c] = v;
  }
  __syncthreads();

  float acc[COUT];
#pragma unroll
  for (int co = 0; co < COUT; ++co) acc[co] = bias[co];
  for (int cin = 0; cin < CIN; ++cin) {
#pragma unroll
    for (int t = 0; t < 9; ++t) {
      const int ky = t / 3, kx = t - ky * 3;
      const float v = tile[cin][ty + ky][tx + kx];
#pragma unroll
      for (int co = 0; co < COUT; ++co)
        acc[co] = fmaf(v, wgt[(co * CIN + cin) * 9 + t], acc[co]);
    }
  }
  const int oh = h0 + ty, ow = w0 + tx;
  unsigned int pk[COUT / 2];
#pragma unroll
  for (int c2 = 0; c2 < COUT / 2; ++c2) {
    float a0 = acc[2 * c2], a1 = acc[2 * c2 + 1];
    if (RELU) { a0 = fmaxf(a0, 0.f); a1 = fmaxf(a1, 0.f); }
    pk[c2] = (unsigned)f2bf(a0) | ((unsigned)f2bf(a1) << 16);
  }
  unsigned short* dst = outp + ((size_t)(b * H + oh) * W + ow) * COUT;
#pragma unroll
  for (int u = 0; u < COUT / 8; ++u)
    *(uint4v*)(dst + u * 8) = uint4v{pk[u * 4], pk[u * 4 + 1], pk[u * 4 + 2], pk[u * 4 + 3]};
}

// ---------------------------------------------------------------------------
// Weight repack into B-fragment order for mfma_f32_16x16x32_bf16.
// k = tap*CINP + cin (CINP mult of 8 so 8-runs stay within one tap).
// ---------------------------------------------------------------------------
template <int CIN, int CINP, int COUT, int KS>
__global__ __launch_bounds__(256) void repack_w(
    const float* __restrict__ w, unsigned short* __restrict__ bp) {
  constexpr int NT = COUT / 16;
  const int idx = blockIdx.x * 256 + threadIdx.x;
  if (idx >= NT * KS * 512) return;
  const int j = idx & 7;
  const int l = (idx >> 3) & 63;
  const int ks = (idx >> 9) % KS;
  const int nt = idx / (KS * 512);
  const int co = nt * 16 + (l & 15);
  const int kglob = ks * 32 + (l >> 4) * 8 + j;
  const int tap = kglob / CINP;
  const int cin = kglob % CINP;
  float v = 0.f;
  if (tap < 9 && cin < CIN) v = w[((size_t)co * CIN + cin) * 9 + tap];
  bp[idx] = f2bf(v);
}

// ---------------------------------------------------------------------------
// Implicit-GEMM 3x3 conv via bf16 MFMA. Packed bf16 NHWC input [H][W][CINP].
// Tile = 32x8 px, 4 waves x 2 rows (round-2/3: 8-row tiles -> 2048 blocks,
// 27 KB LDS -> ~5 resident blocks/CU; convs fell out of the top-5).
// EPI=0: packed bf16 NHWC output [H][W][NT*16] (bias+relu, direct stores).
// EPI=1: fused 1x1 16->19 (intra head) -> packed [H][W][24] (ch19..23=0).
// EPI=2: fused 1x1 32->11 + sigmoid + normalize -> fp32 planes [B][11][HW].
// EPI=3: EPI=2 + fused combine (round-6): keeps g*inv in registers (bit-
//        identical to the gfo store/load round-trip), writes gfo AND does the
//        19-channel spatially-varying stencil -> out0. Kills the standalone
//        combine dispatch (41 us, 57% occ, latency-bound) and its 23 MB gf
//        re-read; combine's memory phase overlaps other blocks' MFMA.
// EDGE19: staging overwrites channel 19 with bf16(edg[pixel]).
// ---------------------------------------------------------------------------
template <int CINP, int KS, int NT, bool EDGE19, int EPI>
__global__ __launch_bounds__(256) void conv3x3_mfma(
    const unsigned short* __restrict__ inp, const float* __restrict__ edg,
    const unsigned short* __restrict__ bpack, const float* __restrict__ bias,
    const float* __restrict__ ew, const float* __restrict__ eb,
    unsigned short* __restrict__ outp, float* __restrict__ outf,
    const float* __restrict__ xin, const unsigned short* __restrict__ ipn,
    float* __restrict__ outc) {
  constexpr int COUT = NT * 16;
  constexpr int CS = (CINP == 16) ? 24 : 40;  // LDS cin stride (16B mult)
  constexpr int EPS = (EPI == 1) ? 24 : 40;   // epilogue LDS px stride
  constexpr int TR = 10;                      // 8 rows + halo
  __shared__ __align__(16) unsigned short tile[TR * 34 * CS];

  const int tid = threadIdx.x;
  const int w0 = blockIdx.x * 32, h0 = blockIdx.y * 8, b = blockIdx.z;

  // ---- stage halo'd tile: packed pixel copy (dwordx4), zero for OOB ----
  for (int idx = tid; idx < TR * 34; idx += 256) {
    const int r = idx / 34, c = idx - r * 34;
    const int gh = h0 + r - 1, gw = w0 + c - 1;
    unsigned short* dst = tile + (size_t)(r * 34 + c) * CS;
    if ((unsigned)gh < (unsigned)H && (unsigned)gw < (unsigned)W) {
      const unsigned short* src = inp + ((size_t)(b * H + gh) * W + gw) * CINP;
#pragma unroll
      for (int u = 0; u < CINP / 8; ++u)
        *(uint4v*)(dst + u * 8) = *(const uint4v*)(src + u * 8);
      if (EDGE19) dst[19] = f2bf(edg[(size_t)b * HW + gh * W + gw]);
    } else {
#pragma unroll
      for (int u = 0; u < CINP / 8; ++u)
        *(uint4v*)(dst + u * 8) = uint4v{0, 0, 0, 0};
    }
  }
  __syncthreads();

  // ---- K-loop (fully unrolled) ----
  const int wv = tid >> 6, lane = tid & 63;
  const int q = lane >> 4, l15 = lane & 15;
  const int rb = wv * 2;

  floatx4 acc[4][NT];
#pragma unroll
  for (int mf = 0; mf < 4; ++mf)
#pragma unroll
    for (int nt = 0; nt < NT; ++nt) acc[mf][nt] = floatx4{0.f, 0.f, 0.f, 0.f};

#pragma unroll
  for (int ks = 0; ks < KS; ++ks) {
    short8 bfrag[NT];
#pragma unroll
    for (int nt = 0; nt < NT; ++nt)
      bfrag[nt] = *(const short8*)(bpack + (size_t)(((nt * KS) + ks) * 64 + lane) * 8);

    const int kbase = ks * 32;  // compile-time
    // per-quad k offset: kq = kbase + q*8 -> tap/cin depend on q (runtime but
    // cheap: q in [0,4), only crosses a tap boundary at known points)
    const int kq = kbase + q * 8;
    int tapq = kq / CINP;
    const int cinq = kq % CINP;
    if (tapq > 8) tapq = 8;  // zero-weight pad region
    const int ky = tapq / 3, kx = tapq - ky * 3;
    const unsigned short* aptr =
        tile + (size_t)((rb + ky) * 34 + (l15 + kx)) * CS + cinq;

#pragma unroll
    for (int mf = 0; mf < 4; ++mf) {
      constexpr int mfs[4][2] = {{0, 0}, {0, 16}, {1, 0}, {1, 16}};
      const int off = (mfs[mf][0] * 34 + mfs[mf][1]) * CS;
      const short8 af = *(const short8*)(aptr + off);
#pragma unroll
      for (int nt = 0; nt < NT; ++nt)
        acc[mf][nt] = __builtin_amdgcn_mfma_f32_16x16x32_bf16(
            af, bfrag[nt], acc[mf][nt], 0, 0, 0);
    }
  }

  if constexpr (EPI == 0) {
    // ---- epilogue: direct bf16 short stores from C-layout registers ----
    // D layout: n (=co within tile) = l15, m (=pixel col) = q*4 + rg.
#pragma unroll
    for (int nt = 0; nt < NT; ++nt) {
      const float bv = bias[nt * 16 + l15];
#pragma unroll
      for (int mf = 0; mf < 4; ++mf) {
        const int row = mf >> 1, colb = (mf & 1) * 16 + q * 4;
        unsigned short* dst =
            outp + ((size_t)(b * H + h0 + rb + row) * W + w0) * COUT + nt * 16 + l15;
#pragma unroll
        for (int rg = 0; rg < 4; ++rg) {
          const float v = fmaxf(acc[mf][nt][rg] + bv, 0.f);
          dst[(size_t)(colb + rg) * COUT] = f2bf(v);
        }
      }
    }
  } else {
    // ---- fused 1x1 epilogue: conv out (bias+relu, bf16) -> LDS ----
    __syncthreads();  // all waves done reading the staging tile
#pragma unroll
    for (int nt = 0; nt < NT; ++nt) {
      const float bv = bias[nt * 16 + l15];
#pragma unroll
      for (int mf = 0; mf < 4; ++mf) {
        const int row = rb + (mf >> 1), colb = (mf & 1) * 16 + q * 4;
#pragma unroll
        for (int rg = 0; rg < 4; ++rg) {
          const int px = row * 32 + colb + rg;
          tile[(size_t)px * EPS + nt * 16 + l15] =
              f2bf(fmaxf(acc[mf][nt][rg] + bv, 0.f));
        }
      }
    }
    __syncthreads();

    {
      const int p = tid;                       // 256 px per tile, 1/thread
      const int gh = h0 + (p >> 5), gw = w0 + (p & 31);
      const unsigned short* src = tile + (size_t)p * EPS;

      if constexpr (EPI == 1) {
        // 1x1 conv 16->19 (no relu), pack to [H][W][24] (ch19..23 = 0)
        float xi[16];
        const uint4v r0 = *(const uint4v*)src;
        const uint4v r1 = *(const uint4v*)(src + 8);
        unpk2(r0.x, xi[0], xi[1]);   unpk2(r0.y, xi[2], xi[3]);
        unpk2(r0.z, xi[4], xi[5]);   unpk2(r0.w, xi[6], xi[7]);
        unpk2(r1.x, xi[8], xi[9]);   unpk2(r1.y, xi[10], xi[11]);
        unpk2(r1.z, xi[12], xi[13]); unpk2(r1.w, xi[14], xi[15]);
        float a[19];
#pragma unroll
        for (int co = 0; co < 19; ++co) a[co] = eb[co];
#pragma unroll
        for (int c = 0; c < 16; ++c) {
          const float v = xi[c];
#pragma unroll
          for (int co = 0; co < 19; ++co) a[co] = fmaf(v, ew[co * 16 + c], a[co]);
        }
        unsigned int pk[12];
#pragma unroll
        for (int j = 0; j < 9; ++j)
          pk[j] = (unsigned)f2bf(a[2 * j]) | ((unsigned)f2bf(a[2 * j + 1]) << 16);
        pk[9] = (unsigned)f2bf(a[18]);
        pk[10] = 0; pk[11] = 0;
        unsigned short* dst = outp + ((size_t)(b * H + gh) * W + gw) * 24;
#pragma unroll
        for (int u = 0; u < 3; ++u)
          *(uint4v*)(dst + u * 8) =
              uint4v{pk[u * 4], pk[u * 4 + 1], pk[u * 4 + 2], pk[u * 4 + 3]};
      } else {
        // 1x1 conv 32->11 + sigmoid + normalize -> fp32 planes [B][11][HW]
        float xi[32];
#pragma unroll
        for (int u = 0; u < 4; ++u) {
          const uint4v r = *(const uint4v*)(src + u * 8);
          unpk2(r.x, xi[u * 8 + 0], xi[u * 8 + 1]);
          unpk2(r.y, xi[u * 8 + 2], xi[u * 8 + 3]);
          unpk2(r.z, xi[u * 8 + 4], xi[u * 8 + 5]);
          unpk2(r.w, xi[u * 8 + 6], xi[u * 8 + 7]);
        }
        float g[11], sum = 0.f;
#pragma unroll
        for (int co = 0; co < 11; ++co) {
          float a = eb[co];
#pragma unroll
          for (int c = 0; c < 32; ++c) a = fmaf(xi[c], ew[co * 32 + c], a);
          g[co] = 1.f / (1.f + expf(-a));
          sum += g[co];
        }
        const float inv = 1.f / (sum + 1e-9f);
        const size_t s = (size_t)gh * W + gw;
#pragma unroll
        for (int co = 0; co < 11; ++co)
          outf[(size_t)(b * 11 + co) * HW + s] = g[co] * inv;

        if constexpr (EPI == 3) {
          // fused combine for this pixel: gn[m] = g[m]*inv is bit-identical
          // to the fp32 store/load of gfo the standalone kernel did.
          float gn[11];
#pragma unroll
          for (int m = 0; m < 11; ++m) gn[m] = g[m] * inv;
          const unsigned short* ip = ipn + ((size_t)b * HW + s) * 24;
          for (int c = 0; c < 19; ++c) {
            const float* xc = xin + (size_t)(b * 19 + c) * HW;
            float r0[3], r1[3], r2[3];
            load_row3(xc, gh - 1, gw, r0);
            load_row3(xc, gh, gw, r1);
            load_row3(xc, gh + 1, gw, r2);
            const float itv = bf2f(ip[c]);
            float a = gn[0] * r1[1];
            a = fmaf(gn[1], r0[0], a);
            a = fmaf(gn[2], r0[1], a);
            a = fmaf(gn[3], r0[2], a);
            a = fmaf(gn[4], r1[0], a);
            a = fmaf(gn[5], r1[2], a);
            a = fmaf(gn[6], r2[0], a);
            a = fmaf(gn[7], r2[1], a);
            a = fmaf(gn[8], r2[2], a);
            a = fmaf(gn[10], itv, a);
            outc[(size_t)(b * 19 + c) * HW + s] = a;
          }
        }
      }
    }
  }
}

// ---------------------------------------------------------------------------
// argmax over 19 channels -> float index, 1 pixel/thread (round-5: grid-size
// is the occupancy cap; 1 px = 2048 blocks = 8 waves/SIMD. Scalar loads are
// still 256 B/wave coalesced).
// ---------------------------------------------------------------------------
__global__ __launch_bounds__(256) void argmax_kernel(
    const float* __restrict__ x, float* __restrict__ sx) {
  const int t = blockIdx.x * 256 + threadIdx.x;  // [0, B*HW)
  const int b = t >> 18;
  const int s = t & (HW - 1);
  const float* xp = x + (size_t)b * 19 * HW + s;
  float bv = *xp;
  float ix = 0.f;
#pragma unroll
  for (int c = 1; c < 19; ++c) {
    const float v = xp[(size_t)c * HW];
    if (v > bv) { bv = v; ix = (float)c; }
  }
  sx[(size_t)b * HW + s] = ix;
}

// 4-wide row load for 2-px-per-thread stencils: r[1] = col w0 (w0 even).
__device__ inline void load_row4(const float* __restrict__ plane, int hh,
                                 int w0, float r[4]) {
#pragma unroll
  for (int i = 0; i < 4; ++i) r[i] = 0.f;
  if ((unsigned)hh < (unsigned)H) {
    const float* rp = plane + (size_t)hh * W + w0;
    const float2 m = *(const float2*)rp;
    r[1] = m.x; r[2] = m.y;
    if (w0 > 0) r[0] = rp[-1];
    if (w0 + 2 < W) r[3] = rp[2];
  }
}

__global__ __launch_bounds__(256) void edge_kernel(
    const float* __restrict__ sx, float* __restrict__ edge) {
  const int t = blockIdx.x * 256 + threadIdx.x;  // [0, B*HW/2)
  const int b = t / (HW / 2);
  const int s2 = (t - b * (HW / 2)) * 2;
  const int h = s2 / W, w0 = s2 - h * W;
  const float* sp = sx + (size_t)b * HW;
  float r0[4], r1[4], r2[4];
  load_row4(sp, h - 1, w0, r0);
  load_row4(sp, h, w0, r1);
  load_row4(sp, h + 1, w0, r2);
  float o[2];
#pragma unroll
  for (int k = 0; k < 2; ++k)
    o[k] = r0[k] + r0[k + 1] + r0[k + 2] + r1[k] + r1[k + 2] + r2[k] +
           r2[k + 1] + r2[k + 2] - 8.f * r1[k + 1];
  *(float2*)(edge + (size_t)b * HW + s2) = float2{o[0], o[1]};
}

// ---------------------------------------------------------------------------
extern "C" void kernel_launch(void* const* d_in, const int* in_sizes, int n_in,
                              void* d_out, int out_size, void* d_ws,
                              size_t ws_size, hipStream_t stream) {
  const float* x     = (const float*)d_in[0];
  const float* image = (const float*)d_in[1];
  const float* iw1 = (const float*)d_in[2];
  const float* ib1 = (const float*)d_in[3];
  const float* iw2 = (const float*)d_in[4];
  const float* ib2 = (const float*)d_in[5];
  const float* iw3 = (const float*)d_in[6];
  const float* ib3 = (const float*)d_in[7];
  const float* gw1 = (const float*)d_in[8];
  const float* gb1 = (const float*)d_in[9];
  const float* gw2 = (const float*)d_in[10];
  const float* gb2 = (const float*)d_in[11];
  const float* gw3 = (const float*)d_in[12];
  const float* gb3 = (const float*)d_in[13];

  // Workspace layout in FLOAT units (1 float = 2 bf16):
  //   sx   [  0,   2)*HW   argmax map
  //   f1p  [  2,  18)*HW   [B][H][W][16] bf16
  //   intp [ 34,  58)*HW   [B][H][W][24] bf16
  //   g1p  [ 58,  90)*HW   [B][H][W][32] bf16
  //   bpacks at 122*HW
  float* ws = (float*)d_ws;
  float* sx = ws;
  unsigned short* f1p  = (unsigned short*)(ws + (size_t)2 * HW);
  unsigned short* intp = (unsigned short*)(ws + (size_t)34 * HW);
  unsigned short* g1p  = (unsigned short*)(ws + (size_t)58 * HW);
  unsigned short* bp_ic2 = (unsigned short*)(ws + (size_t)122 * HW);  // 2560
  unsigned short* bp_gc1 = bp_ic2 + 4096;                             // 7168
  unsigned short* bp_gc2 = bp_gc1 + 12288;                            // 9216

  float* out0 = (float*)d_out;               // (2,19,512,512)
  float* gfo  = out0 + (size_t)2 * 19 * HW;  // (2,11,1,512,512)
  float* edg  = gfo + (size_t)2 * 11 * HW;   // (2,1,512,512)

  const dim3 blk16(16, 16);
  const dim3 grd16(W / 16, H / 16, B);
  const dim3 grdM(W / 32, H / 8, B);     // 32x8 tiles -> 2048 blocks
  const int flat1 = (B * HW) / 256;      // 2048 blocks, 1 px/thread
  const int flat2 = (B * HW / 2) / 256;  // 1024 blocks, 2 px/thread

  argmax_kernel<<<flat1, 256, 0, stream>>>(x, sx);
  edge_kernel<<<flat2, 256, 0, stream>>>(sx, edg);

  repack_w<16, 16, 16, 5><<<10, 256, 0, stream>>>(iw2, bp_ic2);
  repack_w<20, 24, 32, 7><<<28, 256, 0, stream>>>(gw1, bp_gc1);
  repack_w<32, 32, 32, 9><<<36, 256, 0, stream>>>(gw2, bp_gc2);

  conv3x3_fp32_pack<3, 16, true><<<grd16, blk16, 0, stream>>>(image, iw1, ib1, f1p);
  // intra conv2 (16->16) + fused 1x1 16->19 -> packed intra [H][W][24]
  conv3x3_mfma<16, 5, 1, false, 1><<<grdM, 256, 0, stream>>>(
      f1p, nullptr, bp_ic2, ib2, iw3, ib3, intp, nullptr, nullptr, nullptr, nullptr);
  // guide conv1 (20->32, edge in ch19) -> g1p
  conv3x3_mfma<24, 7, 2, true, 0><<<grdM, 256, 0, stream>>>(
      intp, edg, bp_gc1, gb1, nullptr, nullptr, g1p, nullptr, nullptr, nullptr, nullptr);
  // guide conv2 (32->32) + fused 1x1 32->11 + sigmoid + normalize -> gfo
  // + fused combine -> out0 (replaces the standalone combine dispatch)
  conv3x3_mfma<32, 9, 2, false, 3><<<grdM, 256, 0, stream>>>(
      g1p, nullptr, bp_gc2, gb2, gw3, gb3, nullptr, gfo, x, intp, out0);
}

// Round 7
// 228.846 us; speedup vs baseline: 1.3065x; 1.0390x over previous
//
#include <hip/hip_runtime.h>
#include <math.h>

// Problem constants (fixed by setup_inputs): B=2, C=19, H=W=512, fp32 in/out.
constexpr int H = 512, W = 512, B = 2;
constexpr int HW = H * W;

typedef __attribute__((ext_vector_type(8))) short short8;
typedef __attribute__((ext_vector_type(4))) float floatx4;
typedef __attribute__((ext_vector_type(4))) unsigned int uint4v;

__device__ inline unsigned short f2bf(float f) {
  union { float f; unsigned int u; } x{f};
  const unsigned int u = x.u;
  return (unsigned short)((u + 0x7FFFu + ((u >> 16) & 1u)) >> 16);
}
__device__ inline float bf2f(unsigned short s) {
  union { unsigned int u; float f; } x;
  x.u = (unsigned int)s << 16;
  return x.f;
}
// unpack packed bf16 pair (one dword) -> two floats
__device__ inline void unpk2(unsigned int u, float& lo, float& hi) {
  union { unsigned int u; float f; } a, b;
  a.u = u << 16;
  b.u = u & 0xffff0000u;
  lo = a.f;
  hi = b.f;
}

// 3-wide row load for 1-px stencils: r[1] = col w.
__device__ inline void load_row3(const float* __restrict__ plane, int hh,
                                 int w, float r[3]) {
  r[0] = 0.f; r[1] = 0.f; r[2] = 0.f;
  if ((unsigned)hh < (unsigned)H) {
    const float* rp = plane + (size_t)hh * W + w;
    r[1] = rp[0];
    if (w > 0) r[0] = rp[-1];
    if (w + 1 < W) r[2] = rp[1];
  }
}

// ---------------------------------------------------------------------------
// fp32 tiled 3x3 conv 3->16, writes bf16 NHWC packed output [B][H][W][16].
// ---------------------------------------------------------------------------
template <int CIN, int COUT, bool RELU>
__global__ __launch_bounds__(256) void conv3x3_fp32_pack(
    const float* __restrict__ in0, const float* __restrict__ wgt,
    const float* __restrict__ bias, unsigned short* __restrict__ outp) {
  constexpr int TS = 16, TH = 18, LDW = 20;
  __shared__ float tile[CIN][TH][LDW];
  const int tx = threadIdx.x, ty = threadIdx.y;
  const int tid = ty * 16 + tx;
  const int w0 = blockIdx.x * TS, h0 = blockIdx.y * TS, b = blockIdx.z;

  for (int idx = tid; idx < CIN * TH * TH; idx += 256) {
    const int cin = idx / (TH * TH);
    const int rem = idx - cin * (TH * TH);
    const int r = rem / TH, c = rem - r * TH;
    const int gh = h0 + r - 1, gw = w0 + c - 1;
    float v = 0.f;
    if ((unsigned)gh < (unsigned)H && (unsigned)gw < (unsigned)W)
      v = in0[(size_t)(b * CIN + cin) * HW + gh * W + gw];
    tile[cin][r][c] = v;
  }
  __syncthreads();

  float acc[COUT];
#pragma unroll
  for (int co = 0; co < COUT; ++co) acc[co] = bias[co];
  for (int cin = 0; cin < CIN; ++cin) {
#pragma unroll
    for (int t = 0; t < 9; ++t) {
      const int ky = t / 3, kx = t - ky * 3;
      const float v = tile[cin][ty + ky][tx + kx];
#pragma unroll
      for (int co = 0; co < COUT; ++co)
        acc[co] = fmaf(v, wgt[(co * CIN + cin) * 9 + t], acc[co]);
    }
  }
  const int oh = h0 + ty, ow = w0 + tx;
  unsigned int pk[COUT / 2];
#pragma unroll
  for (int c2 = 0; c2 < COUT / 2; ++c2) {
    float a0 = acc[2 * c2], a1 = acc[2 * c2 + 1];
    if (RELU) { a0 = fmaxf(a0, 0.f); a1 = fmaxf(a1, 0.f); }
    pk[c2] = (unsigned)f2bf(a0) | ((unsigned)f2bf(a1) << 16);
  }
  unsigned short* dst = outp + ((size_t)(b * H + oh) * W + ow) * COUT;
#pragma unroll
  for (int u = 0; u < COUT / 8; ++u)
    *(uint4v*)(dst + u * 8) = uint4v{pk[u * 4], pk[u * 4 + 1], pk[u * 4 + 2], pk[u * 4 + 3]};
}

// ---------------------------------------------------------------------------
// Weight repack into B-fragment order for mfma_f32_16x16x32_bf16.
// k = tap*CINP + cin (CINP mult of 8 so 8-runs stay within one tap).
// Round-7: 3 launches merged into one kernel (launch overhead was ~30% of
// wall time across 9 serialized dispatches).
// ---------------------------------------------------------------------------
template <int CIN, int CINP, int COUT, int KS>
__device__ inline void repack_body(int idx, const float* __restrict__ w,
                                   unsigned short* __restrict__ bp) {
  constexpr int NT = COUT / 16;
  if (idx >= NT * KS * 512) return;
  const int j = idx & 7;
  const int l = (idx >> 3) & 63;
  const int ks = (idx >> 9) % KS;
  const int nt = idx / (KS * 512);
  const int co = nt * 16 + (l & 15);
  const int kglob = ks * 32 + (l >> 4) * 8 + j;
  const int tap = kglob / CINP;
  const int cin = kglob % CINP;
  float v = 0.f;
  if (tap < 9 && cin < CIN) v = w[((size_t)co * CIN + cin) * 9 + tap];
  bp[idx] = f2bf(v);
}

__global__ __launch_bounds__(256) void repack_all(
    const float* __restrict__ iw2, const float* __restrict__ gw1,
    const float* __restrict__ gw2, unsigned short* __restrict__ bp_ic2,
    unsigned short* __restrict__ bp_gc1, unsigned short* __restrict__ bp_gc2) {
  const int blk = blockIdx.x, tid = threadIdx.x;
  if (blk < 10) {
    repack_body<16, 16, 16, 5>(blk * 256 + tid, iw2, bp_ic2);
  } else if (blk < 38) {
    repack_body<20, 24, 32, 7>((blk - 10) * 256 + tid, gw1, bp_gc1);
  } else {
    repack_body<32, 32, 32, 9>((blk - 38) * 256 + tid, gw2, bp_gc2);
  }
}

// ---------------------------------------------------------------------------
// Implicit-GEMM 3x3 conv via bf16 MFMA. Packed bf16 NHWC input [H][W][CINP].
// Tile = 32x8 px, 4 waves x 2 rows (round-2/3: 8-row tiles -> 2048 blocks,
// 27 KB LDS -> ~5 resident blocks/CU; convs fell out of the top-5).
// EPI=0: packed bf16 NHWC output [H][W][NT*16] (bias+relu, direct stores).
// EPI=1: fused 1x1 16->19 (intra head) -> packed [H][W][24] (ch19..23=0).
// EPI=2: fused 1x1 32->11 + sigmoid + normalize -> fp32 planes [B][11][HW].
// EPI=3: EPI=2 + fused combine (round-6): keeps g*inv in registers (bit-
//        identical to the gfo store/load round-trip), writes gfo AND does the
//        19-channel spatially-varying stencil -> out0.
// EDGE19 (round-7): edg param = argmax map sx; the 3x3 Laplacian is computed
//        inline during staging (sx is 2 MB, L2-resident) and written BOTH to
//        LDS ch19 and to the edge output plane (outf). Halo pixels get
//        duplicate identical writes - benign. Replaces the edge_kernel
//        dispatch entirely.
// ---------------------------------------------------------------------------
template <int CINP, int KS, int NT, bool EDGE19, int EPI>
__global__ __launch_bounds__(256) void conv3x3_mfma(
    const unsigned short* __restrict__ inp, const float* __restrict__ edg,
    const unsigned short* __restrict__ bpack, const float* __restrict__ bias,
    const float* __restrict__ ew, const float* __restrict__ eb,
    unsigned short* __restrict__ outp, float* __restrict__ outf,
    const float* __restrict__ xin, const unsigned short* __restrict__ ipn,
    float* __restrict__ outc) {
  constexpr int COUT = NT * 16;
  constexpr int CS = (CINP == 16) ? 24 : 40;  // LDS cin stride (16B mult)
  constexpr int EPS = (EPI == 1) ? 24 : 40;   // epilogue LDS px stride
  constexpr int TR = 10;                      // 8 rows + halo
  __shared__ __align__(16) unsigned short tile[TR * 34 * CS];

  const int tid = threadIdx.x;
  const int w0 = blockIdx.x * 32, h0 = blockIdx.y * 8, b = blockIdx.z;

  // ---- stage halo'd tile: packed pixel copy (dwordx4), zero for OOB ----
  for (int idx = tid; idx < TR * 34; idx += 256) {
    const int r = idx / 34, c = idx - r * 34;
    const int gh = h0 + r - 1, gw = w0 + c - 1;
    unsigned short* dst = tile + (size_t)(r * 34 + c) * CS;
    if ((unsigned)gh < (unsigned)H && (unsigned)gw < (unsigned)W) {
      const unsigned short* src = inp + ((size_t)(b * H + gh) * W + gw) * CINP;
#pragma unroll
      for (int u = 0; u < CINP / 8; ++u)
        *(uint4v*)(dst + u * 8) = *(const uint4v*)(src + u * 8);
      if (EDGE19) {
        // inline Laplacian of the argmax map (exact integer fp32 sums)
        const float* sp = edg + (size_t)b * HW;
        float r0[3], r1[3], r2[3];
        load_row3(sp, gh - 1, gw, r0);
        load_row3(sp, gh, gw, r1);
        load_row3(sp, gh + 1, gw, r2);
        const float e = r0[0] + r0[1] + r0[2] + r1[0] + r1[2] + r2[0] +
                        r2[1] + r2[2] - 8.f * r1[1];
        dst[19] = f2bf(e);
        outf[(size_t)b * HW + (size_t)gh * W + gw] = e;
      }
    } else {
#pragma unroll
      for (int u = 0; u < CINP / 8; ++u)
        *(uint4v*)(dst + u * 8) = uint4v{0, 0, 0, 0};
    }
  }
  __syncthreads();

  // ---- K-loop (fully unrolled) ----
  const int wv = tid >> 6, lane = tid & 63;
  const int q = lane >> 4, l15 = lane & 15;
  const int rb = wv * 2;

  floatx4 acc[4][NT];
#pragma unroll
  for (int mf = 0; mf < 4; ++mf)
#pragma unroll
    for (int nt = 0; nt < NT; ++nt) acc[mf][nt] = floatx4{0.f, 0.f, 0.f, 0.f};

#pragma unroll
  for (int ks = 0; ks < KS; ++ks) {
    short8 bfrag[NT];
#pragma unroll
    for (int nt = 0; nt < NT; ++nt)
      bfrag[nt] = *(const short8*)(bpack + (size_t)(((nt * KS) + ks) * 64 + lane) * 8);

    const int kbase = ks * 32;  // compile-time
    // per-quad k offset: kq = kbase + q*8 -> tap/cin depend on q (runtime but
    // cheap: q in [0,4), only crosses a tap boundary at known points)
    const int kq = kbase + q * 8;
    int tapq = kq / CINP;
    const int cinq = kq % CINP;
    if (tapq > 8) tapq = 8;  // zero-weight pad region
    const int ky = tapq / 3, kx = tapq - ky * 3;
    const unsigned short* aptr =
        tile + (size_t)((rb + ky) * 34 + (l15 + kx)) * CS + cinq;

#pragma unroll
    for (int mf = 0; mf < 4; ++mf) {
      constexpr int mfs[4][2] = {{0, 0}, {0, 16}, {1, 0}, {1, 16}};
      const int off = (mfs[mf][0] * 34 + mfs[mf][1]) * CS;
      const short8 af = *(const short8*)(aptr + off);
#pragma unroll
      for (int nt = 0; nt < NT; ++nt)
        acc[mf][nt] = __builtin_amdgcn_mfma_f32_16x16x32_bf16(
            af, bfrag[nt], acc[mf][nt], 0, 0, 0);
    }
  }

  if constexpr (EPI == 0) {
    // ---- epilogue: direct bf16 short stores from C-layout registers ----
    // D layout: n (=co within tile) = l15, m (=pixel col) = q*4 + rg.
#pragma unroll
    for (int nt = 0; nt < NT; ++nt) {
      const float bv = bias[nt * 16 + l15];
#pragma unroll
      for (int mf = 0; mf < 4; ++mf) {
        const int row = mf >> 1, colb = (mf & 1) * 16 + q * 4;
        unsigned short* dst =
            outp + ((size_t)(b * H + h0 + rb + row) * W + w0) * COUT + nt * 16 + l15;
#pragma unroll
        for (int rg = 0; rg < 4; ++rg) {
          const float v = fmaxf(acc[mf][nt][rg] + bv, 0.f);
          dst[(size_t)(colb + rg) * COUT] = f2bf(v);
        }
      }
    }
  } else {
    // ---- fused 1x1 epilogue: conv out (bias+relu, bf16) -> LDS ----
    __syncthreads();  // all waves done reading the staging tile
#pragma unroll
    for (int nt = 0; nt < NT; ++nt) {
      const float bv = bias[nt * 16 + l15];
#pragma unroll
      for (int mf = 0; mf < 4; ++mf) {
        const int row = rb + (mf >> 1), colb = (mf & 1) * 16 + q * 4;
#pragma unroll
        for (int rg = 0; rg < 4; ++rg) {
          const int px = row * 32 + colb + rg;
          tile[(size_t)px * EPS + nt * 16 + l15] =
              f2bf(fmaxf(acc[mf][nt][rg] + bv, 0.f));
        }
      }
    }
    __syncthreads();

    {
      const int p = tid;                       // 256 px per tile, 1/thread
      const int gh = h0 + (p >> 5), gw = w0 + (p & 31);
      const unsigned short* src = tile + (size_t)p * EPS;

      if constexpr (EPI == 1) {
        // 1x1 conv 16->19 (no relu), pack to [H][W][24] (ch19..23 = 0)
        float xi[16];
        const uint4v r0 = *(const uint4v*)src;
        const uint4v r1 = *(const uint4v*)(src + 8);
        unpk2(r0.x, xi[0], xi[1]);   unpk2(r0.y, xi[2], xi[3]);
        unpk2(r0.z, xi[4], xi[5]);   unpk2(r0.w, xi[6], xi[7]);
        unpk2(r1.x, xi[8], xi[9]);   unpk2(r1.y, xi[10], xi[11]);
        unpk2(r1.z, xi[12], xi[13]); unpk2(r1.w, xi[14], xi[15]);
        float a[19];
#pragma unroll
        for (int co = 0; co < 19; ++co) a[co] = eb[co];
#pragma unroll
        for (int c = 0; c < 16; ++c) {
          const float v = xi[c];
#pragma unroll
          for (int co = 0; co < 19; ++co) a[co] = fmaf(v, ew[co * 16 + c], a[co]);
        }
        unsigned int pk[12];
#pragma unroll
        for (int j = 0; j < 9; ++j)
          pk[j] = (unsigned)f2bf(a[2 * j]) | ((unsigned)f2bf(a[2 * j + 1]) << 16);
        pk[9] = (unsigned)f2bf(a[18]);
        pk[10] = 0; pk[11] = 0;
        unsigned short* dst = outp + ((size_t)(b * H + gh) * W + gw) * 24;
#pragma unroll
        for (int u = 0; u < 3; ++u)
          *(uint4v*)(dst + u * 8) =
              uint4v{pk[u * 4], pk[u * 4 + 1], pk[u * 4 + 2], pk[u * 4 + 3]};
      } else {
        // 1x1 conv 32->11 + sigmoid + normalize -> fp32 planes [B][11][HW]
        float xi[32];
#pragma unroll
        for (int u = 0; u < 4; ++u) {
          const uint4v r = *(const uint4v*)(src + u * 8);
          unpk2(r.x, xi[u * 8 + 0], xi[u * 8 + 1]);
          unpk2(r.y, xi[u * 8 + 2], xi[u * 8 + 3]);
          unpk2(r.z, xi[u * 8 + 4], xi[u * 8 + 5]);
          unpk2(r.w, xi[u * 8 + 6], xi[u * 8 + 7]);
        }
        float g[11], sum = 0.f;
#pragma unroll
        for (int co = 0; co < 11; ++co) {
          float a = eb[co];
#pragma unroll
          for (int c = 0; c < 32; ++c) a = fmaf(xi[c], ew[co * 32 + c], a);
          g[co] = 1.f / (1.f + expf(-a));
          sum += g[co];
        }
        const float inv = 1.f / (sum + 1e-9f);
        const size_t s = (size_t)gh * W + gw;
#pragma unroll
        for (int co = 0; co < 11; ++co)
          outf[(size_t)(b * 11 + co) * HW + s] = g[co] * inv;

        if constexpr (EPI == 3) {
          // fused combine for this pixel: gn[m] = g[m]*inv is bit-identical
          // to the fp32 store/load of gfo the standalone kernel did.
          float gn[11];
#pragma unroll
          for (int m = 0; m < 11; ++m) gn[m] = g[m] * inv;
          const unsigned short* ip = ipn + ((size_t)b * HW + s) * 24;
          for (int c = 0; c < 19; ++c) {
            const float* xc = xin + (size_t)(b * 19 + c) * HW;
            float r0[3], r1[3], r2[3];
            load_row3(xc, gh - 1, gw, r0);
            load_row3(xc, gh, gw, r1);
            load_row3(xc, gh + 1, gw, r2);
            const float itv = bf2f(ip[c]);
            float a = gn[0] * r1[1];
            a = fmaf(gn[1], r0[0], a);
            a = fmaf(gn[2], r0[1], a);
            a = fmaf(gn[3], r0[2], a);
            a = fmaf(gn[4], r1[0], a);
            a = fmaf(gn[5], r1[2], a);
            a = fmaf(gn[6], r2[0], a);
            a = fmaf(gn[7], r2[1], a);
            a = fmaf(gn[8], r2[2], a);
            a = fmaf(gn[10], itv, a);
            outc[(size_t)(b * 19 + c) * HW + s] = a;
          }
        }
      }
    }
  }
}

// ---------------------------------------------------------------------------
// argmax over 19 channels -> float index, 1 pixel/thread (round-5: grid-size
// is the occupancy cap; 1 px = 2048 blocks = 8 waves/SIMD. Scalar loads are
// still 256 B/wave coalesced).
// ---------------------------------------------------------------------------
__global__ __launch_bounds__(256) void argmax_kernel(
    const float* __restrict__ x, float* __restrict__ sx) {
  const int t = blockIdx.x * 256 + threadIdx.x;  // [0, B*HW)
  const int b = t >> 18;
  const int s = t & (HW - 1);
  const float* xp = x + (size_t)b * 19 * HW + s;
  float bv = *xp;
  float ix = 0.f;
#pragma unroll
  for (int c = 1; c < 19; ++c) {
    const float v = xp[(size_t)c * HW];
    if (v > bv) { bv = v; ix = (float)c; }
  }
  sx[(size_t)b * HW + s] = ix;
}

// ---------------------------------------------------------------------------
extern "C" void kernel_launch(void* const* d_in, const int* in_sizes, int n_in,
                              void* d_out, int out_size, void* d_ws,
                              size_t ws_size, hipStream_t stream) {
  const float* x     = (const float*)d_in[0];
  const float* image = (const float*)d_in[1];
  const float* iw1 = (const float*)d_in[2];
  const float* ib1 = (const float*)d_in[3];
  const float* iw2 = (const float*)d_in[4];
  const float* ib2 = (const float*)d_in[5];
  const float* iw3 = (const float*)d_in[6];
  const float* ib3 = (const float*)d_in[7];
  const float* gw1 = (const float*)d_in[8];
  const float* gb1 = (const float*)d_in[9];
  const float* gw2 = (const float*)d_in[10];
  const float* gb2 = (const float*)d_in[11];
  const float* gw3 = (const float*)d_in[12];
  const float* gb3 = (const float*)d_in[13];

  // Workspace layout in FLOAT units (1 float = 2 bf16):
  //   sx   [  0,   2)*HW   argmax map
  //   f1p  [  2,  18)*HW   [B][H][W][16] bf16
  //   intp [ 34,  58)*HW   [B][H][W][24] bf16
  //   g1p  [ 58,  90)*HW   [B][H][W][32] bf16
  //   bpacks at 122*HW
  float* ws = (float*)d_ws;
  float* sx = ws;
  unsigned short* f1p  = (unsigned short*)(ws + (size_t)2 * HW);
  unsigned short* intp = (unsigned short*)(ws + (size_t)34 * HW);
  unsigned short* g1p  = (unsigned short*)(ws + (size_t)58 * HW);
  unsigned short* bp_ic2 = (unsigned short*)(ws + (size_t)122 * HW);  // 2560
  unsigned short* bp_gc1 = bp_ic2 + 4096;                             // 7168
  unsigned short* bp_gc2 = bp_gc1 + 12288;                            // 9216

  float* out0 = (float*)d_out;               // (2,19,512,512)
  float* gfo  = out0 + (size_t)2 * 19 * HW;  // (2,11,1,512,512)
  float* edg  = gfo + (size_t)2 * 11 * HW;   // (2,1,512,512)

  const dim3 blk16(16, 16);
  const dim3 grd16(W / 16, H / 16, B);
  const dim3 grdM(W / 32, H / 8, B);     // 32x8 tiles -> 2048 blocks
  const int flat1 = (B * HW) / 256;      // 2048 blocks, 1 px/thread

  // 6 dispatches (was 9): argmax, repack_all, pack, conv16, conv24(+edge),
  // conv32(+1x1+combine).
  argmax_kernel<<<flat1, 256, 0, stream>>>(x, sx);
  repack_all<<<74, 256, 0, stream>>>(iw2, gw1, gw2, bp_ic2, bp_gc1, bp_gc2);

  conv3x3_fp32_pack<3, 16, true><<<grd16, blk16, 0, stream>>>(image, iw1, ib1, f1p);
  // intra conv2 (16->16) + fused 1x1 16->19 -> packed intra [H][W][24]
  conv3x3_mfma<16, 5, 1, false, 1><<<grdM, 256, 0, stream>>>(
      f1p, nullptr, bp_ic2, ib2, iw3, ib3, intp, nullptr, nullptr, nullptr, nullptr);
  // guide conv1 (20->32) + inline edge from sx (writes edg output) -> g1p
  conv3x3_mfma<24, 7, 2, true, 0><<<grdM, 256, 0, stream>>>(
      intp, sx, bp_gc1, gb1, nullptr, nullptr, g1p, edg, nullptr, nullptr, nullptr);
  // guide conv2 (32->32) + fused 1x1 32->11 + sigmoid + normalize -> gfo
  // + fused combine -> out0
  conv3x3_mfma<32, 9, 2, false, 3><<<grdM, 256, 0, stream>>>(
      g1p, nullptr, bp_gc2, gb2, gw3, gb3, nullptr, gfo, x, intp, out0);
}

// Round 8
// 224.795 us; speedup vs baseline: 1.3300x; 1.0180x over previous
//
#include <hip/hip_runtime.h>
#include <math.h>

// Problem constants (fixed by setup_inputs): B=2, C=19, H=W=512, fp32 in/out.
constexpr int H = 512, W = 512, B = 2;
constexpr int HW = H * W;

typedef __attribute__((ext_vector_type(8))) short short8;
typedef __attribute__((ext_vector_type(4))) float floatx4;
typedef __attribute__((ext_vector_type(4))) unsigned int uint4v;

__device__ inline unsigned short f2bf(float f) {
  union { float f; unsigned int u; } x{f};
  const unsigned int u = x.u;
  return (unsigned short)((u + 0x7FFFu + ((u >> 16) & 1u)) >> 16);
}
__device__ inline float bf2f(unsigned short s) {
  union { unsigned int u; float f; } x;
  x.u = (unsigned int)s << 16;
  return x.f;
}
// unpack packed bf16 pair (one dword) -> two floats
__device__ inline void unpk2(unsigned int u, float& lo, float& hi) {
  union { unsigned int u; float f; } a, b;
  a.u = u << 16;
  b.u = u & 0xffff0000u;
  lo = a.f;
  hi = b.f;
}

// 3-wide row load for 1-px stencils: r[1] = col w.
__device__ inline void load_row3(const float* __restrict__ plane, int hh,
                                 int w, float r[3]) {
  r[0] = 0.f; r[1] = 0.f; r[2] = 0.f;
  if ((unsigned)hh < (unsigned)H) {
    const float* rp = plane + (size_t)hh * W + w;
    r[1] = rp[0];
    if (w > 0) r[0] = rp[-1];
    if (w + 1 < W) r[2] = rp[1];
  }
}

// ---------------------------------------------------------------------------
// fp32 tiled 3x3 conv 3->16, writes bf16 NHWC packed output [B][H][W][16].
// ---------------------------------------------------------------------------
template <int CIN, int COUT, bool RELU>
__global__ __launch_bounds__(256) void conv3x3_fp32_pack(
    const float* __restrict__ in0, const float* __restrict__ wgt,
    const float* __restrict__ bias, unsigned short* __restrict__ outp) {
  constexpr int TS = 16, TH = 18, LDW = 20;
  __shared__ float tile[CIN][TH][LDW];
  const int tx = threadIdx.x, ty = threadIdx.y;
  const int tid = ty * 16 + tx;
  const int w0 = blockIdx.x * TS, h0 = blockIdx.y * TS, b = blockIdx.z;

  for (int idx = tid; idx < CIN * TH * TH; idx += 256) {
    const int cin = idx / (TH * TH);
    const int rem = idx - cin * (TH * TH);
    const int r = rem / TH, c = rem - r * TH;
    const int gh = h0 + r - 1, gw = w0 + c - 1;
    float v = 0.f;
    if ((unsigned)gh < (unsigned)H && (unsigned)gw < (unsigned)W)
      v = in0[(size_t)(b * CIN + cin) * HW + gh * W + gw];
    tile[cin][r][c] = v;
  }
  __syncthreads();

  float acc[COUT];
#pragma unroll
  for (int co = 0; co < COUT; ++co) acc[co] = bias[co];
  for (int cin = 0; cin < CIN; ++cin) {
#pragma unroll
    for (int t = 0; t < 9; ++t) {
      const int ky = t / 3, kx = t - ky * 3;
      const float v = tile[cin][ty + ky][tx + kx];
#pragma unroll
      for (int co = 0; co < COUT; ++co)
        acc[co] = fmaf(v, wgt[(co * CIN + cin) * 9 + t], acc[co]);
    }
  }
  const int oh = h0 + ty, ow = w0 + tx;
  unsigned int pk[COUT / 2];
#pragma unroll
  for (int c2 = 0; c2 < COUT / 2; ++c2) {
    float a0 = acc[2 * c2], a1 = acc[2 * c2 + 1];
    if (RELU) { a0 = fmaxf(a0, 0.f); a1 = fmaxf(a1, 0.f); }
    pk[c2] = (unsigned)f2bf(a0) | ((unsigned)f2bf(a1) << 16);
  }
  unsigned short* dst = outp + ((size_t)(b * H + oh) * W + ow) * COUT;
#pragma unroll
  for (int u = 0; u < COUT / 8; ++u)
    *(uint4v*)(dst + u * 8) = uint4v{pk[u * 4], pk[u * 4 + 1], pk[u * 4 + 2], pk[u * 4 + 3]};
}

// ---------------------------------------------------------------------------
// Weight repack into B-fragment order for mfma_f32_16x16x32_bf16.
// k = tap*CINP + cin (CINP mult of 8 so 8-runs stay within one tap).
// 3 launches merged into one kernel (round-7, ~3 us/dispatch boundary).
// ---------------------------------------------------------------------------
template <int CIN, int CINP, int COUT, int KS>
__device__ inline void repack_body(int idx, const float* __restrict__ w,
                                   unsigned short* __restrict__ bp) {
  constexpr int NT = COUT / 16;
  if (idx >= NT * KS * 512) return;
  const int j = idx & 7;
  const int l = (idx >> 3) & 63;
  const int ks = (idx >> 9) % KS;
  const int nt = idx / (KS * 512);
  const int co = nt * 16 + (l & 15);
  const int kglob = ks * 32 + (l >> 4) * 8 + j;
  const int tap = kglob / CINP;
  const int cin = kglob % CINP;
  float v = 0.f;
  if (tap < 9 && cin < CIN) v = w[((size_t)co * CIN + cin) * 9 + tap];
  bp[idx] = f2bf(v);
}

__global__ __launch_bounds__(256) void repack_all(
    const float* __restrict__ iw2, const float* __restrict__ gw1,
    const float* __restrict__ gw2, unsigned short* __restrict__ bp_ic2,
    unsigned short* __restrict__ bp_gc1, unsigned short* __restrict__ bp_gc2) {
  const int blk = blockIdx.x, tid = threadIdx.x;
  if (blk < 10) {
    repack_body<16, 16, 16, 5>(blk * 256 + tid, iw2, bp_ic2);
  } else if (blk < 38) {
    repack_body<20, 24, 32, 7>((blk - 10) * 256 + tid, gw1, bp_gc1);
  } else {
    repack_body<32, 32, 32, 9>((blk - 38) * 256 + tid, gw2, bp_gc2);
  }
}

// ---------------------------------------------------------------------------
// Implicit-GEMM 3x3 conv via bf16 MFMA. Packed bf16 NHWC input [H][W][CINP].
// Tile = 32x8 px, 4 waves x 2 rows; 2048 blocks, 27 KB LDS (~5 blocks/CU).
// EPI=0: packed bf16 NHWC output [H][W][NT*16] (bias+relu, direct stores).
// EPI=1: fused 1x1 16->19 (intra head) -> packed [H][W][24] (ch19..23=0).
// EPI=2: fused 1x1 32->11 + sigmoid + normalize -> fp32 planes [B][11][HW].
// EPI=3: EPI=2 + fused combine. Round-8: the combine stencil reads now go
//        through LDS: after the 1x1 consumes the conv-out bounce buffer, the
//        same LDS is re-used to stage x's 19x10x34 fp32 stencil window
//        (25.8 KB < 27.2 KB) with coalesced cooperative loads (6460 per
//        block vs 43776 predicated scalar gathers = 6.8x fewer load
//        instructions; staged values are exact copies -> bit-identical).
//        The sigmoid/normalize VALU work overlaps the staging latency.
// EDGE19: edg = argmax map sx; inline 3x3 Laplacian during staging, written
//        to LDS ch19 and the edge output plane (halo rewrites benign).
// ---------------------------------------------------------------------------
template <int CINP, int KS, int NT, bool EDGE19, int EPI>
__global__ __launch_bounds__(256) void conv3x3_mfma(
    const unsigned short* __restrict__ inp, const float* __restrict__ edg,
    const unsigned short* __restrict__ bpack, const float* __restrict__ bias,
    const float* __restrict__ ew, const float* __restrict__ eb,
    unsigned short* __restrict__ outp, float* __restrict__ outf,
    const float* __restrict__ xin, const unsigned short* __restrict__ ipn,
    float* __restrict__ outc) {
  constexpr int COUT = NT * 16;
  constexpr int CS = (CINP == 16) ? 24 : 40;  // LDS cin stride (16B mult)
  constexpr int EPS = (EPI == 1) ? 24 : 40;   // epilogue LDS px stride
  constexpr int TR = 10;                      // 8 rows + halo
  __shared__ __align__(16) unsigned short tile[TR * 34 * CS];

  const int tid = threadIdx.x;
  const int w0 = blockIdx.x * 32, h0 = blockIdx.y * 8, b = blockIdx.z;

  // ---- stage halo'd tile: packed pixel copy (dwordx4), zero for OOB ----
  for (int idx = tid; idx < TR * 34; idx += 256) {
    const int r = idx / 34, c = idx - r * 34;
    const int gh = h0 + r - 1, gw = w0 + c - 1;
    unsigned short* dst = tile + (size_t)(r * 34 + c) * CS;
    if ((unsigned)gh < (unsigned)H && (unsigned)gw < (unsigned)W) {
      const unsigned short* src = inp + ((size_t)(b * H + gh) * W + gw) * CINP;
#pragma unroll
      for (int u = 0; u < CINP / 8; ++u)
        *(uint4v*)(dst + u * 8) = *(const uint4v*)(src + u * 8);
      if (EDGE19) {
        // inline Laplacian of the argmax map (exact integer fp32 sums)
        const float* sp = edg + (size_t)b * HW;
        float r0[3], r1[3], r2[3];
        load_row3(sp, gh - 1, gw, r0);
        load_row3(sp, gh, gw, r1);
        load_row3(sp, gh + 1, gw, r2);
        const float e = r0[0] + r0[1] + r0[2] + r1[0] + r1[2] + r2[0] +
                        r2[1] + r2[2] - 8.f * r1[1];
        dst[19] = f2bf(e);
        outf[(size_t)b * HW + (size_t)gh * W + gw] = e;
      }
    } else {
#pragma unroll
      for (int u = 0; u < CINP / 8; ++u)
        *(uint4v*)(dst + u * 8) = uint4v{0, 0, 0, 0};
    }
  }
  __syncthreads();

  // ---- K-loop (fully unrolled) ----
  const int wv = tid >> 6, lane = tid & 63;
  const int q = lane >> 4, l15 = lane & 15;
  const int rb = wv * 2;

  floatx4 acc[4][NT];
#pragma unroll
  for (int mf = 0; mf < 4; ++mf)
#pragma unroll
    for (int nt = 0; nt < NT; ++nt) acc[mf][nt] = floatx4{0.f, 0.f, 0.f, 0.f};

#pragma unroll
  for (int ks = 0; ks < KS; ++ks) {
    short8 bfrag[NT];
#pragma unroll
    for (int nt = 0; nt < NT; ++nt)
      bfrag[nt] = *(const short8*)(bpack + (size_t)(((nt * KS) + ks) * 64 + lane) * 8);

    const int kbase = ks * 32;  // compile-time
    // per-quad k offset: kq = kbase + q*8 -> tap/cin depend on q (runtime but
    // cheap: q in [0,4), only crosses a tap boundary at known points)
    const int kq = kbase + q * 8;
    int tapq = kq / CINP;
    const int cinq = kq % CINP;
    if (tapq > 8) tapq = 8;  // zero-weight pad region
    const int ky = tapq / 3, kx = tapq - ky * 3;
    const unsigned short* aptr =
        tile + (size_t)((rb + ky) * 34 + (l15 + kx)) * CS + cinq;

#pragma unroll
    for (int mf = 0; mf < 4; ++mf) {
      constexpr int mfs[4][2] = {{0, 0}, {0, 16}, {1, 0}, {1, 16}};
      const int off = (mfs[mf][0] * 34 + mfs[mf][1]) * CS;
      const short8 af = *(const short8*)(aptr + off);
#pragma unroll
      for (int nt = 0; nt < NT; ++nt)
        acc[mf][nt] = __builtin_amdgcn_mfma_f32_16x16x32_bf16(
            af, bfrag[nt], acc[mf][nt], 0, 0, 0);
    }
  }

  if constexpr (EPI == 0) {
    // ---- epilogue: direct bf16 short stores from C-layout registers ----
    // D layout: n (=co within tile) = l15, m (=pixel col) = q*4 + rg.
#pragma unroll
    for (int nt = 0; nt < NT; ++nt) {
      const float bv = bias[nt * 16 + l15];
#pragma unroll
      for (int mf = 0; mf < 4; ++mf) {
        const int row = mf >> 1, colb = (mf & 1) * 16 + q * 4;
        unsigned short* dst =
            outp + ((size_t)(b * H + h0 + rb + row) * W + w0) * COUT + nt * 16 + l15;
#pragma unroll
        for (int rg = 0; rg < 4; ++rg) {
          const float v = fmaxf(acc[mf][nt][rg] + bv, 0.f);
          dst[(size_t)(colb + rg) * COUT] = f2bf(v);
        }
      }
    }
  } else {
    // ---- fused 1x1 epilogue: conv out (bias+relu, bf16) -> LDS ----
    __syncthreads();  // all waves done reading the staging tile
#pragma unroll
    for (int nt = 0; nt < NT; ++nt) {
      const float bv = bias[nt * 16 + l15];
#pragma unroll
      for (int mf = 0; mf < 4; ++mf) {
        const int row = rb + (mf >> 1), colb = (mf & 1) * 16 + q * 4;
#pragma unroll
        for (int rg = 0; rg < 4; ++rg) {
          const int px = row * 32 + colb + rg;
          tile[(size_t)px * EPS + nt * 16 + l15] =
              f2bf(fmaxf(acc[mf][nt][rg] + bv, 0.f));
        }
      }
    }
    __syncthreads();

    {
      const int p = tid;                       // 256 px per tile, 1/thread
      const int gh = h0 + (p >> 5), gw = w0 + (p & 31);
      const unsigned short* src = tile + (size_t)p * EPS;

      if constexpr (EPI == 1) {
        // 1x1 conv 16->19 (no relu), pack to [H][W][24] (ch19..23 = 0)
        float xi[16];
        const uint4v r0 = *(const uint4v*)src;
        const uint4v r1 = *(const uint4v*)(src + 8);
        unpk2(r0.x, xi[0], xi[1]);   unpk2(r0.y, xi[2], xi[3]);
        unpk2(r0.z, xi[4], xi[5]);   unpk2(r0.w, xi[6], xi[7]);
        unpk2(r1.x, xi[8], xi[9]);   unpk2(r1.y, xi[10], xi[11]);
        unpk2(r1.z, xi[12], xi[13]); unpk2(r1.w, xi[14], xi[15]);
        float a[19];
#pragma unroll
        for (int co = 0; co < 19; ++co) a[co] = eb[co];
#pragma unroll
        for (int c = 0; c < 16; ++c) {
          const float v = xi[c];
#pragma unroll
          for (int co = 0; co < 19; ++co) a[co] = fmaf(v, ew[co * 16 + c], a[co]);
        }
        unsigned int pk[12];
#pragma unroll
        for (int j = 0; j < 9; ++j)
          pk[j] = (unsigned)f2bf(a[2 * j]) | ((unsigned)f2bf(a[2 * j + 1]) << 16);
        pk[9] = (unsigned)f2bf(a[18]);
        pk[10] = 0; pk[11] = 0;
        unsigned short* dst = outp + ((size_t)(b * H + gh) * W + gw) * 24;
#pragma unroll
        for (int u = 0; u < 3; ++u)
          *(uint4v*)(dst + u * 8) =
              uint4v{pk[u * 4], pk[u * 4 + 1], pk[u * 4 + 2], pk[u * 4 + 3]};
      } else {
        // 1x1 conv 32->11 + sigmoid + normalize -> fp32 planes [B][11][HW]
        float xi[32];
#pragma unroll
        for (int u = 0; u < 4; ++u) {
          const uint4v r = *(const uint4v*)(src + u * 8);
          unpk2(r.x, xi[u * 8 + 0], xi[u * 8 + 1]);
          unpk2(r.y, xi[u * 8 + 2], xi[u * 8 + 3]);
          unpk2(r.z, xi[u * 8 + 4], xi[u * 8 + 5]);
          unpk2(r.w, xi[u * 8 + 6], xi[u * 8 + 7]);
        }

        if constexpr (EPI == 3) {
          // all threads have their conv-out in registers; tile is now free.
          __syncthreads();
        }

        float g[11], sum = 0.f;
#pragma unroll
        for (int co = 0; co < 11; ++co) {
          float a = eb[co];
#pragma unroll
          for (int c = 0; c < 32; ++c) a = fmaf(xi[c], ew[co * 32 + c], a);
          g[co] = 1.f / (1.f + expf(-a));
          sum += g[co];
        }
        const float inv = 1.f / (sum + 1e-9f);
        const size_t s = (size_t)gh * W + gw;
#pragma unroll
        for (int co = 0; co < 11; ++co)
          outf[(size_t)(b * 11 + co) * HW + s] = g[co] * inv;

        if constexpr (EPI == 3) {
          // ---- stage x stencil window into LDS (exact copies) ----
          // xs[c][r][col] : 19 x 10 x 34 fp32 = 25840 B  (tile = 27200 B)
          float* xs = (float*)tile;
          for (int idx = tid; idx < 19 * 10 * 34; idx += 256) {
            const int c = idx / 340;
            const int rem = idx - c * 340;
            const int r = rem / 34, col = rem - r * 34;
            const int gh2 = h0 + r - 1, gw2 = w0 + col - 1;
            float v = 0.f;
            if ((unsigned)gh2 < (unsigned)H && (unsigned)gw2 < (unsigned)W)
              v = xin[(size_t)(b * 19 + c) * HW + (size_t)gh2 * W + gw2];
            xs[idx] = v;
          }
          __syncthreads();

          // fused combine for this pixel: gn[m] = g[m]*inv is bit-identical
          // to the fp32 store/load of gfo the standalone kernel did.
          float gn[11];
#pragma unroll
          for (int m = 0; m < 11; ++m) gn[m] = g[m] * inv;
          const int pr = p >> 5, pc = p & 31;
          const unsigned short* ip = ipn + ((size_t)b * HW + s) * 24;
          for (int c = 0; c < 19; ++c) {
            const float* xc = xs + c * 340;
            const float* x0 = xc + (pr + 0) * 34 + pc;  // row gh-1
            const float* x1 = xc + (pr + 1) * 34 + pc;  // row gh
            const float* x2 = xc + (pr + 2) * 34 + pc;  // row gh+1
            const float itv = bf2f(ip[c]);
            float a = gn[0] * x1[1];
            a = fmaf(gn[1], x0[0], a);
            a = fmaf(gn[2], x0[1], a);
            a = fmaf(gn[3], x0[2], a);
            a = fmaf(gn[4], x1[0], a);
            a = fmaf(gn[5], x1[2], a);
            a = fmaf(gn[6], x2[0], a);
            a = fmaf(gn[7], x2[1], a);
            a = fmaf(gn[8], x2[2], a);
            a = fmaf(gn[10], itv, a);
            outc[(size_t)(b * 19 + c) * HW + s] = a;
          }
        }
      }
    }
  }
}

// ---------------------------------------------------------------------------
// argmax over 19 channels -> float index, 1 pixel/thread (round-5: grid-size
// is the occupancy cap; 1 px = 2048 blocks = 8 waves/SIMD. Scalar loads are
// still 256 B/wave coalesced).
// ---------------------------------------------------------------------------
__global__ __launch_bounds__(256) void argmax_kernel(
    const float* __restrict__ x, float* __restrict__ sx) {
  const int t = blockIdx.x * 256 + threadIdx.x;  // [0, B*HW)
  const int b = t >> 18;
  const int s = t & (HW - 1);
  const float* xp = x + (size_t)b * 19 * HW + s;
  float bv = *xp;
  float ix = 0.f;
#pragma unroll
  for (int c = 1; c < 19; ++c) {
    const float v = xp[(size_t)c * HW];
    if (v > bv) { bv = v; ix = (float)c; }
  }
  sx[(size_t)b * HW + s] = ix;
}

// ---------------------------------------------------------------------------
extern "C" void kernel_launch(void* const* d_in, const int* in_sizes, int n_in,
                              void* d_out, int out_size, void* d_ws,
                              size_t ws_size, hipStream_t stream) {
  const float* x     = (const float*)d_in[0];
  const float* image = (const float*)d_in[1];
  const float* iw1 = (const float*)d_in[2];
  const float* ib1 = (const float*)d_in[3];
  const float* iw2 = (const float*)d_in[4];
  const float* ib2 = (const float*)d_in[5];
  const float* iw3 = (const float*)d_in[6];
  const float* ib3 = (const float*)d_in[7];
  const float* gw1 = (const float*)d_in[8];
  const float* gb1 = (const float*)d_in[9];
  const float* gw2 = (const float*)d_in[10];
  const float* gb2 = (const float*)d_in[11];
  const float* gw3 = (const float*)d_in[12];
  const float* gb3 = (const float*)d_in[13];

  // Workspace layout in FLOAT units (1 float = 2 bf16):
  //   sx   [  0,   2)*HW   argmax map
  //   f1p  [  2,  18)*HW   [B][H][W][16] bf16
  //   intp [ 34,  58)*HW   [B][H][W][24] bf16
  //   g1p  [ 58,  90)*HW   [B][H][W][32] bf16
  //   bpacks at 122*HW
  float* ws = (float*)d_ws;
  float* sx = ws;
  unsigned short* f1p  = (unsigned short*)(ws + (size_t)2 * HW);
  unsigned short* intp = (unsigned short*)(ws + (size_t)34 * HW);
  unsigned short* g1p  = (unsigned short*)(ws + (size_t)58 * HW);
  unsigned short* bp_ic2 = (unsigned short*)(ws + (size_t)122 * HW);  // 2560
  unsigned short* bp_gc1 = bp_ic2 + 4096;                             // 7168
  unsigned short* bp_gc2 = bp_gc1 + 12288;                            // 9216

  float* out0 = (float*)d_out;               // (2,19,512,512)
  float* gfo  = out0 + (size_t)2 * 19 * HW;  // (2,11,1,512,512)
  float* edg  = gfo + (size_t)2 * 11 * HW;   // (2,1,512,512)

  const dim3 blk16(16, 16);
  const dim3 grd16(W / 16, H / 16, B);
  const dim3 grdM(W / 32, H / 8, B);     // 32x8 tiles -> 2048 blocks
  const int flat1 = (B * HW) / 256;      // 2048 blocks, 1 px/thread

  // 6 dispatches: argmax, repack_all, pack, conv16, conv24(+edge),
  // conv32(+1x1+combine).
  argmax_kernel<<<flat1, 256, 0, stream>>>(x, sx);
  repack_all<<<74, 256, 0, stream>>>(iw2, gw1, gw2, bp_ic2, bp_gc1, bp_gc2);

  conv3x3_fp32_pack<3, 16, true><<<grd16, blk16, 0, stream>>>(image, iw1, ib1, f1p);
  // intra conv2 (16->16) + fused 1x1 16->19 -> packed intra [H][W][24]
  conv3x3_mfma<16, 5, 1, false, 1><<<grdM, 256, 0, stream>>>(
      f1p, nullptr, bp_ic2, ib2, iw3, ib3, intp, nullptr, nullptr, nullptr, nullptr);
  // guide conv1 (20->32) + inline edge from sx (writes edg output) -> g1p
  conv3x3_mfma<24, 7, 2, true, 0><<<grdM, 256, 0, stream>>>(
      intp, sx, bp_gc1, gb1, nullptr, nullptr, g1p, edg, nullptr, nullptr, nullptr);
  // guide conv2 (32->32) + fused 1x1 32->11 + sigmoid + normalize -> gfo
  // + fused combine (LDS-staged x stencil) -> out0
  conv3x3_mfma<32, 9, 2, false, 3><<<grdM, 256, 0, stream>>>(
      g1p, nullptr, bp_gc2, gb2, gw3, gb3, nullptr, gfo, x, intp, out0);
}